// Round 5
// baseline (9844.221 us; speedup 1.0000x reference)
//
#include <hip/hip_runtime.h>
#include <math.h>

#define B 512
#define S 64
#define T 32
#define E 512
#define H 1024
#define VOUTD 128
#define H2 (2*H)
#define H3 (3*H)
#define H6 (6*H)

typedef unsigned short ushortT;
typedef unsigned int uintT;
typedef __attribute__((ext_vector_type(8))) short short8;
typedef __attribute__((ext_vector_type(4))) float floatx4;

__device__ __forceinline__ float sigmoidf_(float x) { return 1.0f / (1.0f + expf(-x)); }

__device__ __forceinline__ uintT pack_hi2(float a, float b) {
    return (__float_as_uint(a) >> 16) | (__float_as_uint(b) & 0xFFFF0000u);
}
__device__ __forceinline__ uintT pack_lo2(float a, float b) {
    uintT ua = __float_as_uint(a), ub = __float_as_uint(b);
    uintT la = __float_as_uint(a - __uint_as_float(ua & 0xFFFF0000u)) >> 16;
    uintT lb = __float_as_uint(b - __uint_as_float(ub & 0xFFFF0000u)) >> 16;
    return la | (lb << 16);
}

__global__ __launch_bounds__(256) void zero16(uint4* __restrict__ p, int n)
{
    int i = blockIdx.x * 256 + threadIdx.x;
    if (i < n) p[i] = make_uint4(0u, 0u, 0u, 0u);
}

// ===========================================================================
// W -> fragment-major hi/lo planes. COALESCED: one wave per fragment.
// Fragment f = (jb*ncK + c)*3 + g; 1024 shorts (hi 512 | lo 512).
// Lane l: jl=l&15, kq=l>>4 reads W[g*nj + jb*16 + jl][c*32 + kq*8 .. +8)
// (16 rows x 128B contiguous per wave) and writes out[f*1024 + l*8] (hi)
// and +512 (lo): 2x 1KB fully contiguous per wave -> no write amplification.
// NOTE: ncK = K/32 = 1 << (kShift-2)  =>  jb = rest >> (kShift-2).
// (R4 bug: used kShift-5, sending jb OOB -> GPU fault.)
// ===========================================================================
__global__ __launch_bounds__(256) void swizzle_w(
    const float* __restrict__ W, ushortT* __restrict__ out, int njShift, int kShift)
{
    const int K = 8 << kShift;
    const int nj = 1 << njShift;
    const int ncK = K >> 5;
    const int total = (nj >> 4) * ncK * 3;
    int f = blockIdx.x * 4 + (threadIdx.x >> 6);
    if (f >= total) return;
    const int lane = threadIdx.x & 63;
    int g = f % 3;
    int rest = f / 3;
    int c = rest & (ncK - 1);
    int jb = rest >> (kShift - 2);
    int jl = lane & 15, kq = lane >> 4;
    int row = g * nj + jb * 16 + jl;
    int k = c * 32 + kq * 8;
    const float* s = W + (size_t)row * K + k;
    float4 f0 = *(const float4*)s;
    float4 f1 = *(const float4*)(s + 4);
    uint4 hv = make_uint4(pack_hi2(f0.x, f0.y), pack_hi2(f0.z, f0.w),
                          pack_hi2(f1.x, f1.y), pack_hi2(f1.z, f1.w));
    uint4 lv = make_uint4(pack_lo2(f0.x, f0.y), pack_lo2(f0.z, f0.w),
                          pack_lo2(f1.x, f1.y), pack_lo2(f1.z, f1.w));
    size_t base = (size_t)f * 1024 + (size_t)lane * 8;
    *(uint4*)(out + base) = hv;
    *(uint4*)(out + base + 512) = lv;
}

// ===========================================================================
// Pipeline macros for the fused step kernels (issue-early schedule).
// Per pair (2 K-chunks): after the barrier, ds_write the B-pair loaded a full
// iteration ago, issue B loads for pair+2 and A loads for pair+1, then MFMA
// the current pair. Every global load gets a full compute phase before the
// compiler's vmcnt(0) drain at the next barrier.
// ===========================================================================
#define MFMA16(a, b, c) __builtin_amdgcn_mfma_f32_16x16x32_bf16(a, b, c, 0, 0, 0)

#define CHUNK_MFMA(PB, CLOC, ACUR)                                              \
    {                                                                           \
        const ushortT* bp = &sB[PB][(CLOC) * 12 * 512];                         \
        _Pragma("unroll")                                                       \
        for (int g = 0; g < 3; ++g) {                                           \
            short8 bhf = *(const short8*)&bp[rb0 + g * 1024];                   \
            short8 blf = *(const short8*)&bp[rb0 + g * 1024 + 512];             \
            acc[0][g] = MFMA16(ACUR[(CLOC)*4+0], bhf, acc[0][g]);               \
            acc[0][g] = MFMA16(ACUR[(CLOC)*4+0], blf, acc[0][g]);               \
            acc[0][g] = MFMA16(ACUR[(CLOC)*4+1], bhf, acc[0][g]);               \
            acc[1][g] = MFMA16(ACUR[(CLOC)*4+2], bhf, acc[1][g]);               \
            acc[1][g] = MFMA16(ACUR[(CLOC)*4+2], blf, acc[1][g]);               \
            acc[1][g] = MFMA16(ACUR[(CLOC)*4+3], bhf, acc[1][g]);               \
        }                                                                       \
    }

#define PAIR_BODY(IP, ACUR, BRDY, ANXT, BFLY, PB)                               \
    {                                                                           \
        if ((IP) + 2 < NP) {                                                    \
            _Pragma("unroll")                                                   \
            for (int k = 0; k < 3; ++k) {                                       \
                BFLY[k]     = *(const uint4*)(gWb[k] + (size_t)(2*(IP)+4) * 3072); \
                BFLY[3 + k] = *(const uint4*)(gWb[k] + (size_t)(2*(IP)+5) * 3072); \
            }                                                                   \
        }                                                                       \
        if ((IP) + 1 < NP) {                                                    \
            _Pragma("unroll")                                                   \
            for (int c = 0; c < 2; ++c) {                                       \
                const ushortT* ap_ = aP + (size_t)(2*(IP)+2 + c) * 1024;        \
                ANXT[c*4+0] = *(const short8*)(ap_);                            \
                ANXT[c*4+1] = *(const short8*)(ap_ + 512);                      \
                ANXT[c*4+2] = *(const short8*)(ap_ + NCKd * 1024);              \
                ANXT[c*4+3] = *(const short8*)(ap_ + NCKd * 1024 + 512);        \
            }                                                                   \
            _Pragma("unroll")                                                   \
            for (int k = 0; k < 3; ++k) {                                       \
                *(uint4*)&sB[(PB) ^ 1][lds0[k]] = BRDY[k];                      \
                *(uint4*)&sB[(PB) ^ 1][lds1[k]] = BRDY[3 + k];                  \
            }                                                                   \
        }                                                                       \
        CHUNK_MFMA(PB, 0, ACUR);                                                \
        CHUNK_MFMA(PB, 1, ACUR);                                                \
        __syncthreads();                                                        \
    }

// ===========================================================================
// FUSED encoder step (issue-early pipeline). Block: 64 rows x 32 j, 4 waves.
// ===========================================================================
__global__ __launch_bounds__(256) void fused_step_enc(
    const ushortT* __restrict__ Afr,
    const ushortT* __restrict__ WfrF, const ushortT* __restrict__ WfrB,
    const float* __restrict__ giTabF, const float* __restrict__ giTabB,
    const int* __restrict__ src, int s,
    const float* __restrict__ bhF, const float* __restrict__ bhB,
    float* __restrict__ h, ushortT* __restrict__ AfrOut)
{
    __shared__ ushortT sB[2][24 * 512];
    __shared__ int sTok[64];
    const int t = threadIdx.x, lane = t & 63, w = t >> 6;
    const int bid = blockIdx.x;
    const int xcd = bid & 7, q = bid >> 3;
    const int jg = xcd + 8 * (q & 3);     // [0,32)
    const int mb = q >> 2;                // [0,16)
    const int j0 = jg * 32, m0 = mb * 64;
    const bool bwd = (m0 >= B);
    const ushortT* Wfr = bwd ? WfrB : WfrF;
    const float* giTab = bwd ? giTabB : giTabF;
    const float* bh = bwd ? bhB : bhF;
    const int NCKd = 32, NP = 16;

    if (t < 64) {
        int b = (m0 + t) & (B - 1);
        sTok[t] = src[b * S + (bwd ? (S - 1 - s) : s)];
    }

    const int wr = w >> 1, wc = w & 1;
    const ushortT* aP = Afr + (size_t)((m0 >> 4) + wr * 2) * (NCKd * 1024) + lane * 8;

    const ushortT* gWb[3];
    int lds0[3], lds1[3];
#pragma unroll
    for (int k = 0; k < 3; ++k) {
        int f = w * 3 + k;
        int jbLoc = f / 6, rem = f % 6;
        gWb[k] = Wfr + (size_t)(jg * 2 + jbLoc) * (NCKd * 3072) + rem * 512 + lane * 8;
        lds0[k] = f * 512 + lane * 8;
        lds1[k] = (12 + f) * 512 + lane * 8;
    }
    const int rb0 = wc * 3072 + lane * 8;

    floatx4 acc[2][3];
#pragma unroll
    for (int mi = 0; mi < 2; ++mi)
#pragma unroll
        for (int g = 0; g < 3; ++g) acc[mi][g] = (floatx4){0.f, 0.f, 0.f, 0.f};

    short8 aA[8], aB[8];
    uint4 bA[6], bB[6];

    // prologue: pair0 B -> LDS buf0; pair0 A -> aA; pair1 B -> bA
    {
        uint4 p0[6];
#pragma unroll
        for (int k = 0; k < 3; ++k) {
            p0[k]     = *(const uint4*)(gWb[k]);
            p0[3 + k] = *(const uint4*)(gWb[k] + 3072);
        }
#pragma unroll
        for (int c = 0; c < 2; ++c) {
            const ushortT* ap_ = aP + (size_t)c * 1024;
            aA[c*4+0] = *(const short8*)(ap_);
            aA[c*4+1] = *(const short8*)(ap_ + 512);
            aA[c*4+2] = *(const short8*)(ap_ + NCKd * 1024);
            aA[c*4+3] = *(const short8*)(ap_ + NCKd * 1024 + 512);
        }
#pragma unroll
        for (int k = 0; k < 3; ++k) {
            bA[k]     = *(const uint4*)(gWb[k] + 2 * 3072);
            bA[3 + k] = *(const uint4*)(gWb[k] + 3 * 3072);
        }
#pragma unroll
        for (int k = 0; k < 3; ++k) {
            *(uint4*)&sB[0][lds0[k]] = p0[k];
            *(uint4*)&sB[0][lds1[k]] = p0[3 + k];
        }
    }
    __syncthreads();

    for (int ip = 0; ip < NP; ip += 2) {
        PAIR_BODY(ip,     aA, bA, aB, bB, 0);
        PAIR_BODY(ip + 1, aB, bB, aA, bA, 1);
    }

    // fused gate epilogue
    const int colj = j0 + wc * 16 + (lane & 15);
    const float bR = bh[colj], bZ = bh[H + colj], bN = bh[2 * H + colj];
    const int rloc0 = wr * 32 + (lane >> 4) * 4;
    const int cA = colj >> 5;
    const int kqA = (colj >> 3) & 3;
    const int eA = colj & 7;
#pragma unroll
    for (int mi = 0; mi < 2; ++mi) {
#pragma unroll
        for (int r = 0; r < 4; ++r) {
            const int rloc = rloc0 + mi * 16 + r;
            const int row = m0 + rloc;
            const float* gi = giTab + (size_t)sTok[rloc] * H3;
            float ghr = acc[mi][0][r] + bR;
            float ghz = acc[mi][1][r] + bZ;
            float ghn = acc[mi][2][r] + bN;
            float rr = sigmoidf_(gi[colj] + ghr);
            float z  = sigmoidf_(gi[H + colj] + ghz);
            float n  = tanhf(gi[2 * H + colj] + rr * ghn);
            const size_t idx = (size_t)row * H + colj;
            float hnew = (1.0f - z) * n + z * h[idx];
            h[idx] = hnew;
            uintT u = __float_as_uint(hnew);
            size_t ao = (((size_t)(row >> 4) * 32 + cA) * 2) * 512
                      + (size_t)((row & 15) + 16 * kqA) * 8 + eA;
            AfrOut[ao] = (ushortT)(u >> 16);
            AfrOut[ao + 512] = (ushortT)(__float_as_uint(hnew - __uint_as_float(u & 0xFFFF0000u)) >> 16);
        }
    }
}

// ===========================================================================
// FUSED decoder step (issue-early pipeline): Hd = 2H, gates {j, 2H+j, 4H+j}.
// ===========================================================================
__global__ __launch_bounds__(256) void fused_step_dec(
    const ushortT* __restrict__ Afr, const ushortT* __restrict__ Wfr,
    const float* __restrict__ giTabD, const int* __restrict__ tok,
    const float* __restrict__ bhD,
    float* __restrict__ h, ushortT* __restrict__ AfrOut)
{
    __shared__ ushortT sB[2][24 * 512];
    __shared__ int sTok[64];
    const int t = threadIdx.x, lane = t & 63, w = t >> 6;
    const int bid = blockIdx.x;
    const int xcd = bid & 7, q = bid >> 3;
    const int jg = xcd + 8 * (q & 7);     // [0,64)
    const int mb = q >> 3;                // [0,8)
    const int j0 = jg * 32, m0 = mb * 64;
    const int NCKd = 64, NP = 32;

    if (t < 64) sTok[t] = tok[m0 + t];

    const int wr = w >> 1, wc = w & 1;
    const ushortT* aP = Afr + (size_t)((m0 >> 4) + wr * 2) * (NCKd * 1024) + lane * 8;

    const ushortT* gWb[3];
    int lds0[3], lds1[3];
#pragma unroll
    for (int k = 0; k < 3; ++k) {
        int f = w * 3 + k;
        int jbLoc = f / 6, rem = f % 6;
        gWb[k] = Wfr + (size_t)(jg * 2 + jbLoc) * (NCKd * 3072) + rem * 512 + lane * 8;
        lds0[k] = f * 512 + lane * 8;
        lds1[k] = (12 + f) * 512 + lane * 8;
    }
    const int rb0 = wc * 3072 + lane * 8;

    floatx4 acc[2][3];
#pragma unroll
    for (int mi = 0; mi < 2; ++mi)
#pragma unroll
        for (int g = 0; g < 3; ++g) acc[mi][g] = (floatx4){0.f, 0.f, 0.f, 0.f};

    short8 aA[8], aB[8];
    uint4 bA[6], bB[6];

    {
        uint4 p0[6];
#pragma unroll
        for (int k = 0; k < 3; ++k) {
            p0[k]     = *(const uint4*)(gWb[k]);
            p0[3 + k] = *(const uint4*)(gWb[k] + 3072);
        }
#pragma unroll
        for (int c = 0; c < 2; ++c) {
            const ushortT* ap_ = aP + (size_t)c * 1024;
            aA[c*4+0] = *(const short8*)(ap_);
            aA[c*4+1] = *(const short8*)(ap_ + 512);
            aA[c*4+2] = *(const short8*)(ap_ + NCKd * 1024);
            aA[c*4+3] = *(const short8*)(ap_ + NCKd * 1024 + 512);
        }
#pragma unroll
        for (int k = 0; k < 3; ++k) {
            bA[k]     = *(const uint4*)(gWb[k] + 2 * 3072);
            bA[3 + k] = *(const uint4*)(gWb[k] + 3 * 3072);
        }
#pragma unroll
        for (int k = 0; k < 3; ++k) {
            *(uint4*)&sB[0][lds0[k]] = p0[k];
            *(uint4*)&sB[0][lds1[k]] = p0[3 + k];
        }
    }
    __syncthreads();

    for (int ip = 0; ip < NP; ip += 2) {
        PAIR_BODY(ip,     aA, bA, aB, bB, 0);
        PAIR_BODY(ip + 1, aB, bB, aA, bA, 1);
    }

    const int colj = j0 + wc * 16 + (lane & 15);
    const float bR = bhD[colj], bZ = bhD[H2 + colj], bN = bhD[2 * H2 + colj];
    const int rloc0 = wr * 32 + (lane >> 4) * 4;
    const int cA = colj >> 5;
    const int kqA = (colj >> 3) & 3;
    const int eA = colj & 7;
#pragma unroll
    for (int mi = 0; mi < 2; ++mi) {
#pragma unroll
        for (int r = 0; r < 4; ++r) {
            const int rloc = rloc0 + mi * 16 + r;
            const int row = m0 + rloc;
            const float* gi = giTabD + (size_t)sTok[rloc] * H6;
            float ghr = acc[mi][0][r] + bR;
            float ghz = acc[mi][1][r] + bZ;
            float ghn = acc[mi][2][r] + bN;
            float rr = sigmoidf_(gi[colj] + ghr);
            float z  = sigmoidf_(gi[H2 + colj] + ghz);
            float n  = tanhf(gi[2 * H2 + colj] + rr * ghn);
            const size_t idx = (size_t)row * H2 + colj;
            float hnew = (1.0f - z) * n + z * h[idx];
            h[idx] = hnew;
            uintT u = __float_as_uint(hnew);
            size_t ao = (((size_t)(row >> 4) * 64 + cA) * 2) * 512
                      + (size_t)((row & 15) + 16 * kqA) * 8 + eA;
            AfrOut[ao] = (ushortT)(u >> 16);
            AfrOut[ao + 512] = (ushortT)(__float_as_uint(hnew - __uint_as_float(u & 0xFFFF0000u)) >> 16);
        }
    }
}

// hh fp32 row-major + dec A planes (fragment-major); tok[b]=tgt[b,0]
__global__ __launch_bounds__(256) void init_hh_tok_split(
    const float* __restrict__ h_f, const float* __restrict__ h_b,
    const int* __restrict__ tgt, float* __restrict__ hh,
    ushortT* __restrict__ AfrD, int* __restrict__ tok)
{
    int i = blockIdx.x * blockDim.x + threadIdx.x;   // over B*2H
    int b = i >> 11;
    int j = i & 2047;
    float v = (j < H) ? h_f[(size_t)b * H + j] : h_b[(size_t)b * H + (j - H)];
    hh[i] = v;
    uintT u = __float_as_uint(v);
    size_t ao = (((size_t)(b >> 4) * 64 + (j >> 5)) * 2) * 512
              + (size_t)((b & 15) + 16 * ((j >> 3) & 3)) * 8 + (j & 7);
    AfrD[ao] = (ushortT)(u >> 16);
    AfrD[ao + 512] = (ushortT)(__float_as_uint(v - __uint_as_float(u & 0xFFFF0000u)) >> 16);
    if (j == 0) tok[b] = tgt[b * T];
}

// ===========================================================================
// logits = hh @ W_fc^T + b_fc (V=128) + argmax; 2 rows/block, 256 thr.
// ===========================================================================
__global__ __launch_bounds__(256) void logits_argmax2(
    const float* __restrict__ hh, const float* __restrict__ W_fc,
    const float* __restrict__ b_fc, float* __restrict__ out,
    int* __restrict__ tok, int t)
{
    __shared__ float sh[2][H2];
    __shared__ float sred[2][2][128];
    __shared__ float sval[2][128];
    __shared__ int   sidx[2][128];
    const int tid = threadIdx.x;
    const int col = tid & 127;
    const int kh  = tid >> 7;
    const int b0  = blockIdx.x * 2;

    {
        const float4* srcp = (const float4*)(hh + (size_t)b0 * H2);
        float4* dst = (float4*)sh;
        for (int i = tid; i < 2 * H2 / 4; i += 256) dst[i] = srcp[i];
    }
    __syncthreads();

    const float* wrow = W_fc + (size_t)col * H2 + kh * (H2 / 2);
    const float* s0 = sh[0] + kh * (H2 / 2);
    const float* s1 = sh[1] + kh * (H2 / 2);
    float a0 = 0.f, a1 = 0.f;
#pragma unroll 8
    for (int k = 0; k < H2 / 2; k += 4) {
        float4 w4 = *(const float4*)(wrow + k);
        float4 h0 = *(const float4*)(s0 + k);
        float4 h1 = *(const float4*)(s1 + k);
        a0 += w4.x * h0.x + w4.y * h0.y + w4.z * h0.z + w4.w * h0.w;
        a1 += w4.x * h1.x + w4.y * h1.y + w4.z * h1.z + w4.w * h1.w;
    }
    sred[kh][0][col] = a0;
    sred[kh][1][col] = a1;
    __syncthreads();

    if (kh == 0) {
        float l0 = sred[0][0][col] + sred[1][0][col] + b_fc[col];
        float l1 = sred[0][1][col] + sred[1][1][col] + b_fc[col];
        out[(size_t)(b0 + 0) * ((T - 1) * VOUTD) + (size_t)t * VOUTD + col] = l0;
        out[(size_t)(b0 + 1) * ((T - 1) * VOUTD) + (size_t)t * VOUTD + col] = l1;
        sval[0][col] = l0; sidx[0][col] = col;
        sval[1][col] = l1; sidx[1][col] = col;
    }
    __syncthreads();

    const int r = tid >> 7, c = tid & 127;
    for (int off = 64; off > 0; off >>= 1) {
        if (c < off) {
            float ov = sval[r][c + off]; int oi = sidx[r][c + off];
            if (ov > sval[r][c] || (ov == sval[r][c] && oi < sidx[r][c])) {
                sval[r][c] = ov; sidx[r][c] = oi;
            }
        }
        __syncthreads();
    }
    if (tid < 2) tok[b0 + tid] = sidx[tid][0];
}

// ===========================================================================
// Split-K fp32 GEMM (exact): Cp[z][128,N] = A[:, zKc:(z+1)Kc] @ W[:, ...]^T
// + deterministic combine (sum parts in k-order, then +bias).
// ===========================================================================
__global__ __launch_bounds__(256) void gemm_sk(
    const float* __restrict__ Abase, int lda,
    const float* __restrict__ W, float* __restrict__ Cp, int N, int K, int KS)
{
    __shared__ float As[16][68];
    __shared__ float Ws[16][68];
    const int t = threadIdx.x;
    const int m0 = blockIdx.y * 64, n0 = blockIdx.x * 64;
    const int Kc = K / KS, kb = blockIdx.z * Kc;
    const int lr = t >> 2, lc = (t & 3) << 2;
    const int tx = t & 15, ty = t >> 4;
    const int tn0 = tx << 2, tm0 = ty << 2;
    const float* Aptr = Abase + (size_t)(m0 + lr) * lda + kb;
    const float* Wptr = W + (size_t)(n0 + lr) * K + kb;
    float acc[4][4] = {{0.f}};
    for (int k0 = 0; k0 < Kc; k0 += 16) {
        float4 a4 = *(const float4*)(Aptr + k0 + lc);
        float4 w4 = *(const float4*)(Wptr + k0 + lc);
        __syncthreads();
        As[lc+0][lr] = a4.x; As[lc+1][lr] = a4.y; As[lc+2][lr] = a4.z; As[lc+3][lr] = a4.w;
        Ws[lc+0][lr] = w4.x; Ws[lc+1][lr] = w4.y; Ws[lc+2][lr] = w4.z; Ws[lc+3][lr] = w4.w;
        __syncthreads();
#pragma unroll
        for (int kk = 0; kk < 16; ++kk) {
            float4 av = *(const float4*)&As[kk][tm0];
            float4 wv = *(const float4*)&Ws[kk][tn0];
            float am[4] = {av.x, av.y, av.z, av.w};
            float wn[4] = {wv.x, wv.y, wv.z, wv.w};
#pragma unroll
            for (int i = 0; i < 4; ++i)
#pragma unroll
                for (int j = 0; j < 4; ++j) acc[i][j] += am[i] * wn[j];
        }
    }
    float* Cb = Cp + ((size_t)blockIdx.z * VOUTD + m0 + tm0) * N + n0 + tn0;
#pragma unroll
    for (int i = 0; i < 4; ++i)
        *(float4*)(Cb + (size_t)i * N) = make_float4(acc[i][0], acc[i][1], acc[i][2], acc[i][3]);
}

__global__ __launch_bounds__(256) void gi_combine(
    const float* __restrict__ Cp, const float* __restrict__ bias,
    float* __restrict__ Cout, int N, int KS)
{
    int j = blockIdx.x * 256 + threadIdx.x;
    int v = blockIdx.y;
    float s = 0.f;
    for (int z = 0; z < KS; ++z) s += Cp[((size_t)z * VOUTD + v) * N + j];
    Cout[(size_t)v * N + j] = s + bias[j];
}

// ===========================================================================
// fp32 vector GEMM (fallback path only).
// ===========================================================================
__global__ __launch_bounds__(256) void gemm_bias(
    const float* __restrict__ Abase,
    const int* __restrict__ idx, int idxStride, int idxOff, int lda,
    const float* __restrict__ W, const float* __restrict__ bias,
    float* __restrict__ C, int N, int K)
{
    __shared__ float As[16][68];
    __shared__ float Ws[16][68];
    const int t = threadIdx.x;
    const int m0 = blockIdx.y * 64, n0 = blockIdx.x * 64;
    const int lr = t >> 2, lc = (t & 3) << 2;
    const int tx = t & 15, ty = t >> 4;
    const int tn0 = tx << 2, tm0 = ty << 2;
    const int arow = m0 + lr;
    const float* Aptr = idx ? (Abase + (size_t)idx[arow * idxStride + idxOff] * lda)
                            : (Abase + (size_t)arow * lda);
    const float* Wptr = W + (size_t)(n0 + lr) * K;
    float acc[4][4] = {{0.f}};
    for (int k0 = 0; k0 < K; k0 += 16) {
        float4 a4 = *(const float4*)(Aptr + k0 + lc);
        float4 w4 = *(const float4*)(Wptr + k0 + lc);
        __syncthreads();
        As[lc+0][lr] = a4.x; As[lc+1][lr] = a4.y; As[lc+2][lr] = a4.z; As[lc+3][lr] = a4.w;
        Ws[lc+0][lr] = w4.x; Ws[lc+1][lr] = w4.y; Ws[lc+2][lr] = w4.z; Ws[lc+3][lr] = w4.w;
        __syncthreads();
#pragma unroll
        for (int kk = 0; kk < 16; ++kk) {
            float4 av = *(const float4*)&As[kk][tm0];
            float4 wv = *(const float4*)&Ws[kk][tn0];
            float am[4] = {av.x, av.y, av.z, av.w};
            float wn[4] = {wv.x, wv.y, wv.z, wv.w};
#pragma unroll
            for (int i = 0; i < 4; ++i)
#pragma unroll
                for (int j = 0; j < 4; ++j) acc[i][j] += am[i] * wn[j];
        }
    }
    const float b0 = bias[n0+tn0], b1 = bias[n0+tn0+1], b2 = bias[n0+tn0+2], b3 = bias[n0+tn0+3];
#pragma unroll
    for (int i = 0; i < 4; ++i) {
        float4 o = make_float4(acc[i][0]+b0, acc[i][1]+b1, acc[i][2]+b2, acc[i][3]+b3);
        *(float4*)(C + (size_t)(m0 + tm0 + i) * N + n0 + tn0) = o;
    }
}

__global__ __launch_bounds__(256) void gemm_enc(
    const float* __restrict__ Abase, int lda, int K,
    const int* __restrict__ srcIdx, int s,
    const float* __restrict__ W1, const float* __restrict__ bias1,
    const float* __restrict__ W2, const float* __restrict__ bias2,
    float* __restrict__ C, int N)
{
    __shared__ float As[16][68];
    __shared__ float Ws[16][68];
    const int t = threadIdx.x;
    const int m0 = blockIdx.y * 64, n0 = blockIdx.x * 64;
    const bool bwd = (m0 >= B);
    const float* W = bwd ? W2 : W1;
    const float* bias = bwd ? bias2 : bias1;
    const int lr = t >> 2, lc = (t & 3) << 2;
    const int tx = t & 15, ty = t >> 4;
    const int tn0 = tx << 2, tm0 = ty << 2;
    const int arow = m0 + lr;
    const float* Aptr;
    if (srcIdx) {
        int r = arow & (B - 1);
        int sidx = bwd ? (S - 1 - s) : s;
        Aptr = Abase + (size_t)srcIdx[r * S + sidx] * lda;
    } else Aptr = Abase + (size_t)arow * lda;
    const float* Wptr = W + (size_t)(n0 + lr) * K;
    float acc[4][4] = {{0.f}};
    for (int k0 = 0; k0 < K; k0 += 16) {
        float4 a4 = *(const float4*)(Aptr + k0 + lc);
        float4 w4 = *(const float4*)(Wptr + k0 + lc);
        __syncthreads();
        As[lc+0][lr] = a4.x; As[lc+1][lr] = a4.y; As[lc+2][lr] = a4.z; As[lc+3][lr] = a4.w;
        Ws[lc+0][lr] = w4.x; Ws[lc+1][lr] = w4.y; Ws[lc+2][lr] = w4.z; Ws[lc+3][lr] = w4.w;
        __syncthreads();
#pragma unroll
        for (int kk = 0; kk < 16; ++kk) {
            float4 av = *(const float4*)&As[kk][tm0];
            float4 wv = *(const float4*)&Ws[kk][tn0];
            float am[4] = {av.x, av.y, av.z, av.w};
            float wn[4] = {wv.x, wv.y, wv.z, wv.w};
#pragma unroll
            for (int i = 0; i < 4; ++i)
#pragma unroll
                for (int j = 0; j < 4; ++j) acc[i][j] += am[i] * wn[j];
        }
    }
    const float b0 = bias[n0+tn0], b1 = bias[n0+tn0+1], b2 = bias[n0+tn0+2], b3 = bias[n0+tn0+3];
#pragma unroll
    for (int i = 0; i < 4; ++i) {
        float4 o = make_float4(acc[i][0]+b0, acc[i][1]+b1, acc[i][2]+b2, acc[i][3]+b3);
        *(float4*)(C + (size_t)(m0 + tm0 + i) * N + n0 + tn0) = o;
    }
}

__global__ __launch_bounds__(256) void gru_gate(
    const float* __restrict__ gi, const float* __restrict__ gh,
    float* __restrict__ h, int Hd)
{
    int i = blockIdx.x * blockDim.x + threadIdx.x;
    int b = i / Hd, j = i - b * Hd;
    const float* gib = gi + (size_t)b * 3 * Hd;
    const float* ghb = gh + (size_t)b * 3 * Hd;
    float r = sigmoidf_(gib[j] + ghb[j]);
    float z = sigmoidf_(gib[Hd + j] + ghb[Hd + j]);
    float n = tanhf(gib[2 * Hd + j] + r * ghb[2 * Hd + j]);
    h[i] = (1.0f - z) * n + z * h[i];
}

__global__ __launch_bounds__(256) void init_hh_tok(
    const float* __restrict__ h_f, const float* __restrict__ h_b,
    const int* __restrict__ tgt, float* __restrict__ hh, int* __restrict__ tok)
{
    int i = blockIdx.x * blockDim.x + threadIdx.x;
    int b = i >> 11, j = i & 2047;
    hh[i] = (j < H) ? h_f[(size_t)b * H + j] : h_b[(size_t)b * H + (j - H)];
    if (j == 0) tok[b] = tgt[b * T];
}

// ===========================================================================
extern "C" void kernel_launch(void* const* d_in, const int* in_sizes, int n_in,
                              void* d_out, int out_size, void* d_ws, size_t ws_size,
                              hipStream_t stream)
{
    const int*   src     = (const int*)d_in[0];
    const int*   tgt     = (const int*)d_in[1];
    const float* enc_emb = (const float*)d_in[2];
    const float* dec_emb = (const float*)d_in[3];
    const float* W_ih_f  = (const float*)d_in[4];
    const float* W_hh_f  = (const float*)d_in[5];
    const float* b_ih_f  = (const float*)d_in[6];
    const float* b_hh_f  = (const float*)d_in[7];
    const float* W_ih_b  = (const float*)d_in[8];
    const float* W_hh_b  = (const float*)d_in[9];
    const float* b_ih_b  = (const float*)d_in[10];
    const float* b_hh_b  = (const float*)d_in[11];
    const float* W_ih_d  = (const float*)d_in[12];
    const float* W_hh_d  = (const float*)d_in[13];
    const float* b_ih_d  = (const float*)d_in[14];
    const float* b_hh_d  = (const float*)d_in[15];
    const float* W_fc    = (const float*)d_in[16];
    const float* b_fc    = (const float*)d_in[17];
    float* out = (float*)d_out;

    // ---------------- workspace layout ----------------
    char* base = (char*)d_ws;
    size_t off = 0;
    auto alloc = [&](size_t bytes) { char* p = base + off; off += (bytes + 255) & ~(size_t)255; return p; };

    float*   hE     = (float*)  alloc((size_t)2 * B * H * 4);       // zeroed with AfrEA
    ushortT* AfrEA  = (ushortT*)alloc((size_t)2 * B * H * 2 * 2);   // enc A planes ping
    ushortT* AfrEB  = (ushortT*)alloc((size_t)2 * B * H * 2 * 2);   // enc A planes pong
    float*   hh     = (float*)  alloc((size_t)B * H2 * 4);
    ushortT* AfrDA  = (ushortT*)alloc((size_t)B * H2 * 2 * 2);      // dec A planes ping
    ushortT* AfrDB  = (ushortT*)alloc((size_t)B * H2 * 2 * 2);      // dec A planes pong
    float*   giTabF = (float*)  alloc((size_t)VOUTD * H3 * 4);
    float*   giTabB = (float*)  alloc((size_t)VOUTD * H3 * 4);
    float*   giTabD = (float*)  alloc((size_t)VOUTD * H6 * 4);
    float*   giPart = (float*)  alloc((size_t)4 * VOUTD * H6 * 4);  // split-K partials (12.6MB)
    ushortT* WfrF   = (ushortT*)alloc((size_t)H3 * H * 2 * 2);
    ushortT* WfrB   = (ushortT*)alloc((size_t)H3 * H * 2 * 2);
    ushortT* WfrD   = (ushortT*)alloc((size_t)H6 * H2 * 2 * 2);
    int*     tok    = (int*)    alloc((size_t)B * 4);
    size_t required = off;

    dim3 blk(256);

    if (ws_size >= required) {
        // =================== fragment-major fused path ===================
        {   // zero hE fp32 + AfrEA (contiguous)
            size_t zbytes = (size_t)2 * B * H * 4 + (size_t)2 * B * H * 4;
            int n16 = (int)(zbytes / 16);
            zero16<<<dim3((n16 + 255) / 256), blk, 0, stream>>>((uint4*)hE, n16);
        }
        // W -> fragment-major hi/lo (coalesced, wave per fragment)
        {
            int fe = (H / 16) * (H / 32) * 3;        // 6144
            int fd = (H2 / 16) * (H2 / 32) * 3;      // 24576
            swizzle_w<<<dim3((fe + 3) / 4), blk, 0, stream>>>(W_hh_f, WfrF, 10, 7);
            swizzle_w<<<dim3((fe + 3) / 4), blk, 0, stream>>>(W_hh_b, WfrB, 10, 7);
            swizzle_w<<<dim3((fd + 3) / 4), blk, 0, stream>>>(W_hh_d, WfrD, 11, 8);
        }

        // gi tables (exact fp32, split-K x4)
        gemm_sk<<<dim3(H3 / 64, VOUTD / 64, 4), blk, 0, stream>>>(
            enc_emb, E, W_ih_f, giPart, H3, E, 4);
        gi_combine<<<dim3(H3 / 256, VOUTD), blk, 0, stream>>>(giPart, b_ih_f, giTabF, H3, 4);
        gemm_sk<<<dim3(H3 / 64, VOUTD / 64, 4), blk, 0, stream>>>(
            enc_emb, E, W_ih_b, giPart, H3, E, 4);
        gi_combine<<<dim3(H3 / 256, VOUTD), blk, 0, stream>>>(giPart, b_ih_b, giTabB, H3, 4);
        gemm_sk<<<dim3(H6 / 64, VOUTD / 64, 4), blk, 0, stream>>>(
            dec_emb, E, W_ih_d, giPart, H6, E, 4);
        gi_combine<<<dim3(H6 / 256, VOUTD), blk, 0, stream>>>(giPart, b_ih_d, giTabD, H6, 4);

        // ---------------- Encoder: 64 fused steps ----------------
        for (int s = 0; s < S; ++s) {
            const ushortT* inA = (s & 1) ? AfrEB : AfrEA;
            ushortT* outA = (s & 1) ? AfrEA : AfrEB;
            fused_step_enc<<<dim3(512), blk, 0, stream>>>(
                inA, WfrF, WfrB, giTabF, giTabB, src, s, b_hh_f, b_hh_b, hE, outA);
        }

        init_hh_tok_split<<<dim3((B * H2) / 256), blk, 0, stream>>>(
            hE, hE + (size_t)B * H, tgt, hh, AfrDA, tok);

        // ---------------- Decoder: 31 fused steps ----------------
        for (int t = 0; t < T - 1; ++t) {
            const ushortT* inA = (t & 1) ? AfrDB : AfrDA;
            ushortT* outA = (t & 1) ? AfrDA : AfrDB;
            fused_step_dec<<<dim3(512), blk, 0, stream>>>(
                inA, WfrD, giTabD, tok, b_hh_d, hh, outA);
            logits_argmax2<<<dim3(B / 2), blk, 0, stream>>>(hh, W_fc, b_fc, out, tok, t);
        }
    } else {
        // =================== fp32 fallback (R1-proven path) ===================
        {
            size_t zbytes = (size_t)2 * B * H * 4;
            int n16 = (int)(zbytes / 16);
            zero16<<<dim3((n16 + 255) / 256), blk, 0, stream>>>((uint4*)hE, n16);
        }
        float* giE = (float*)WfrF;                       // scratch overlay
        float* ghF = giE + (size_t)2 * B * H3;
        dim3 grid_gi(H3 / 64, (2 * B) / 64);
        dim3 grid_gate((2 * B * H) / 256);
        for (int s = 0; s < S; ++s) {
            gemm_enc<<<grid_gi, blk, 0, stream>>>(enc_emb, E, E, src, s,
                                                  W_ih_f, b_ih_f, W_ih_b, b_ih_b, giE, H3);
            gemm_enc<<<grid_gi, blk, 0, stream>>>(hE, H, H, nullptr, 0,
                                                  W_hh_f, b_hh_f, W_hh_b, b_hh_b, ghF, H3);
            gru_gate<<<grid_gate, blk, 0, stream>>>(giE, ghF, hE, H);
        }
        init_hh_tok<<<dim3((B * H2) / 256), blk, 0, stream>>>(hE, hE + (size_t)B * H, tgt, hh, tok);
        dim3 grid_d(H6 / 64, B / 64);
        dim3 grid_dgate((B * H2) / 256);
        for (int t = 0; t < T - 1; ++t) {
            gemm_bias<<<grid_d, blk, 0, stream>>>(dec_emb, tok, 1, 0, E,
                                                  W_ih_d, b_ih_d, giE, H6, E);
            gemm_bias<<<grid_d, blk, 0, stream>>>(hh, nullptr, 0, 0, H2,
                                                  W_hh_d, b_hh_d, ghF, H6, H2);
            gru_gate<<<grid_dgate, blk, 0, stream>>>(giE, ghF, hh, H2);
            logits_argmax2<<<dim3(B / 2), blk, 0, stream>>>(hh, W_fc, b_fc, out, tok, t);
        }
    }
}

// Round 6
// 8398.521 us; speedup vs baseline: 1.1721x; 1.1721x over previous
//
#include <hip/hip_runtime.h>
#include <math.h>

#define B 512
#define S 64
#define T 32
#define E 512
#define H 1024
#define VOUTD 128
#define H2 (2*H)
#define H3 (3*H)
#define H6 (6*H)

typedef unsigned short ushortT;
typedef unsigned int uintT;
typedef __attribute__((ext_vector_type(8))) short short8;
typedef __attribute__((ext_vector_type(4))) float floatx4;

__device__ __forceinline__ float sigmoidf_(float x) { return 1.0f / (1.0f + expf(-x)); }

__device__ __forceinline__ uintT pack_hi2(float a, float b) {
    return (__float_as_uint(a) >> 16) | (__float_as_uint(b) & 0xFFFF0000u);
}
__device__ __forceinline__ uintT pack_lo2(float a, float b) {
    uintT ua = __float_as_uint(a), ub = __float_as_uint(b);
    uintT la = __float_as_uint(a - __uint_as_float(ua & 0xFFFF0000u)) >> 16;
    uintT lb = __float_as_uint(b - __uint_as_float(ub & 0xFFFF0000u)) >> 16;
    return la | (lb << 16);
}

__global__ __launch_bounds__(256) void zero16(uint4* __restrict__ p, int n)
{
    int i = blockIdx.x * 256 + threadIdx.x;
    if (i < n) p[i] = make_uint4(0u, 0u, 0u, 0u);
}

// ===========================================================================
// W -> fragment-major hi/lo planes. COALESCED: one wave per fragment.
// Fragment f = (jb*ncK + c)*3 + g; 1024 shorts (hi 512 | lo 512).
// Lane l: jl=l&15, kq=l>>4 reads W[g*nj + jb*16 + jl][c*32 + kq*8 .. +8)
// and writes out[f*1024 + l*8] (hi) and +512 (lo): contiguous 1KB per wave.
// ncK = K/32 = 1 << (kShift-2)  =>  jb = rest >> (kShift-2).
// ===========================================================================
__global__ __launch_bounds__(256) void swizzle_w(
    const float* __restrict__ W, ushortT* __restrict__ out, int njShift, int kShift)
{
    const int K = 8 << kShift;
    const int nj = 1 << njShift;
    const int ncK = K >> 5;
    const int total = (nj >> 4) * ncK * 3;
    int f = blockIdx.x * 4 + (threadIdx.x >> 6);
    if (f >= total) return;
    const int lane = threadIdx.x & 63;
    int g = f % 3;
    int rest = f / 3;
    int c = rest & (ncK - 1);
    int jb = rest >> (kShift - 2);
    int jl = lane & 15, kq = lane >> 4;
    int row = g * nj + jb * 16 + jl;
    int k = c * 32 + kq * 8;
    const float* s = W + (size_t)row * K + k;
    float4 f0 = *(const float4*)s;
    float4 f1 = *(const float4*)(s + 4);
    uint4 hv = make_uint4(pack_hi2(f0.x, f0.y), pack_hi2(f0.z, f0.w),
                          pack_hi2(f1.x, f1.y), pack_hi2(f1.z, f1.w));
    uint4 lv = make_uint4(pack_lo2(f0.x, f0.y), pack_lo2(f0.z, f0.w),
                          pack_lo2(f1.x, f1.y), pack_lo2(f1.z, f1.w));
    size_t base = (size_t)f * 1024 + (size_t)lane * 8;
    *(uint4*)(out + base) = hv;
    *(uint4*)(out + base + 512) = lv;
}

// ===========================================================================
// Main-loop macros: R3-proven schedule. Per pair (2 K-chunks): load pair+1
// B and A registers at body top, run 36 MFMAs (covering the load latency),
// then ds_write the B regs to the spare buffer and take the single barrier.
// ===========================================================================
#define MFMA16(a, b, c) __builtin_amdgcn_mfma_f32_16x16x32_bf16(a, b, c, 0, 0, 0)

#define CHUNK_MFMA(PB, CLOC, ACUR)                                              \
    {                                                                           \
        const ushortT* bp = &sB[PB][(CLOC) * 12 * 512];                         \
        _Pragma("unroll")                                                       \
        for (int g = 0; g < 3; ++g) {                                           \
            short8 bhf = *(const short8*)&bp[rb0 + g * 1024];                   \
            short8 blf = *(const short8*)&bp[rb0 + g * 1024 + 512];             \
            acc[0][g] = MFMA16(ACUR[(CLOC)*4+0], bhf, acc[0][g]);               \
            acc[0][g] = MFMA16(ACUR[(CLOC)*4+0], blf, acc[0][g]);               \
            acc[0][g] = MFMA16(ACUR[(CLOC)*4+1], bhf, acc[0][g]);               \
            acc[1][g] = MFMA16(ACUR[(CLOC)*4+2], bhf, acc[1][g]);               \
            acc[1][g] = MFMA16(ACUR[(CLOC)*4+2], blf, acc[1][g]);               \
            acc[1][g] = MFMA16(ACUR[(CLOC)*4+3], bhf, acc[1][g]);               \
        }                                                                       \
    }

#define PAIR_BODY(IP, ACUR, ANXT, PB)                                           \
    {                                                                           \
        if ((IP) + 1 < NP) {                                                    \
            _Pragma("unroll")                                                   \
            for (int k = 0; k < 3; ++k) {                                       \
                bT[k]     = *(const uint4*)(gWb[k] + (size_t)(2*(IP)+2) * 3072);\
                bT[3 + k] = *(const uint4*)(gWb[k] + (size_t)(2*(IP)+3) * 3072);\
            }                                                                   \
            _Pragma("unroll")                                                   \
            for (int c = 0; c < 2; ++c) {                                       \
                const ushortT* ap_ = aP + (size_t)(2*(IP)+2 + c) * 1024;        \
                ANXT[c*4+0] = *(const short8*)(ap_);                            \
                ANXT[c*4+1] = *(const short8*)(ap_ + 512);                      \
                ANXT[c*4+2] = *(const short8*)(ap_ + NCKd * 1024);              \
                ANXT[c*4+3] = *(const short8*)(ap_ + NCKd * 1024 + 512);        \
            }                                                                   \
        }                                                                       \
        CHUNK_MFMA(PB, 0, ACUR);                                                \
        CHUNK_MFMA(PB, 1, ACUR);                                                \
        if ((IP) + 1 < NP) {                                                    \
            _Pragma("unroll")                                                   \
            for (int k = 0; k < 3; ++k) {                                       \
                *(uint4*)&sB[(PB) ^ 1][lds0[k]] = bT[k];                        \
                *(uint4*)&sB[(PB) ^ 1][lds1[k]] = bT[3 + k];                    \
            }                                                                   \
            __syncthreads();                                                    \
        }                                                                       \
    }

// Coalesced fragment-plane epilogue writer: stage packed shorts into the
// free sB[0] region (last pair reads sB[1]), barrier, stream out 8KB as
// contiguous uint4 (2 per thread). NCKA = ncK of the A-plane buffer.
#define EPILOGUE_STORE(NCKA)                                                    \
    __syncthreads();                                                            \
    _Pragma("unroll")                                                           \
    for (int v = 0; v < 2; ++v) {                                               \
        int idx = t * 2 + v;                                                    \
        int rbo = idx >> 7;                                                     \
        int offs = (idx & 127) * 8;                                             \
        size_t gbase = ((size_t)((m0 >> 4) + rbo) * (NCKA) + cA) * 1024;        \
        *(uint4*)(AfrOut + gbase + offs) = *(const uint4*)&eb[rbo * 1024 + offs]; \
    }

// ===========================================================================
// FUSED encoder step. Block: 64 rows x 32 j, 4 waves (2x2).
// ===========================================================================
__global__ __launch_bounds__(256) void fused_step_enc(
    const ushortT* __restrict__ Afr,
    const ushortT* __restrict__ WfrF, const ushortT* __restrict__ WfrB,
    const float* __restrict__ giTabF, const float* __restrict__ giTabB,
    const int* __restrict__ src, int s,
    const float* __restrict__ bhF, const float* __restrict__ bhB,
    float* __restrict__ h, ushortT* __restrict__ AfrOut)
{
    __shared__ ushortT sB[2][24 * 512];
    __shared__ int sTok[64];
    const int t = threadIdx.x, lane = t & 63, w = t >> 6;
    const int bid = blockIdx.x;
    const int xcd = bid & 7, q = bid >> 3;
    const int jg = xcd + 8 * (q & 3);     // [0,32)
    const int mb = q >> 2;                // [0,16)
    const int j0 = jg * 32, m0 = mb * 64;
    const bool bwd = (m0 >= B);
    const ushortT* Wfr = bwd ? WfrB : WfrF;
    const float* giTab = bwd ? giTabB : giTabF;
    const float* bh = bwd ? bhB : bhF;
    const int NCKd = 32, NP = 16;

    if (t < 64) {
        int b = (m0 + t) & (B - 1);
        sTok[t] = src[b * S + (bwd ? (S - 1 - s) : s)];
    }

    const int wr = w >> 1, wc = w & 1;
    const ushortT* aP = Afr + (size_t)((m0 >> 4) + wr * 2) * (NCKd * 1024) + lane * 8;

    const ushortT* gWb[3];
    int lds0[3], lds1[3];
#pragma unroll
    for (int k = 0; k < 3; ++k) {
        int f = w * 3 + k;
        int jbLoc = f / 6, rem = f % 6;
        gWb[k] = Wfr + (size_t)(jg * 2 + jbLoc) * (NCKd * 3072) + rem * 512 + lane * 8;
        lds0[k] = f * 512 + lane * 8;
        lds1[k] = (12 + f) * 512 + lane * 8;
    }
    const int rb0 = wc * 3072 + lane * 8;

    floatx4 acc[2][3];
#pragma unroll
    for (int mi = 0; mi < 2; ++mi)
#pragma unroll
        for (int g = 0; g < 3; ++g) acc[mi][g] = (floatx4){0.f, 0.f, 0.f, 0.f};

    short8 aA[8], aB[8];
    uint4 bT[6];

    // prologue: pair0 B -> regs -> sB[0]; pair0 A -> aA
    {
        uint4 p0[6];
#pragma unroll
        for (int k = 0; k < 3; ++k) {
            p0[k]     = *(const uint4*)(gWb[k]);
            p0[3 + k] = *(const uint4*)(gWb[k] + 3072);
        }
#pragma unroll
        for (int c = 0; c < 2; ++c) {
            const ushortT* ap_ = aP + (size_t)c * 1024;
            aA[c*4+0] = *(const short8*)(ap_);
            aA[c*4+1] = *(const short8*)(ap_ + 512);
            aA[c*4+2] = *(const short8*)(ap_ + NCKd * 1024);
            aA[c*4+3] = *(const short8*)(ap_ + NCKd * 1024 + 512);
        }
#pragma unroll
        for (int k = 0; k < 3; ++k) {
            *(uint4*)&sB[0][lds0[k]] = p0[k];
            *(uint4*)&sB[0][lds1[k]] = p0[3 + k];
        }
    }
    __syncthreads();

    for (int ip = 0; ip < NP; ip += 2) {
        PAIR_BODY(ip,     aA, aB, 0);
        PAIR_BODY(ip + 1, aB, aA, 1);
    }

    // fused gate epilogue: compute, write h fp32 (coalesced), stage packed
    // bf16 planes into LDS (fragment layout), then coalesced copy-out.
    const int colj = j0 + wc * 16 + (lane & 15);
    const float bR = bh[colj], bZ = bh[H + colj], bN = bh[2 * H + colj];
    const int rloc0 = wr * 32 + (lane >> 4) * 4;
    const int cA = j0 >> 5;
    const int innerB = ((colj >> 3) & 3) * 128 + (colj & 7);
    ushortT* eb = &sB[0][0];
#pragma unroll
    for (int mi = 0; mi < 2; ++mi) {
#pragma unroll
        for (int r = 0; r < 4; ++r) {
            const int rloc = rloc0 + mi * 16 + r;
            const int row = m0 + rloc;
            const float* gi = giTab + (size_t)sTok[rloc] * H3;
            float ghr = acc[mi][0][r] + bR;
            float ghz = acc[mi][1][r] + bZ;
            float ghn = acc[mi][2][r] + bN;
            float rr = sigmoidf_(gi[colj] + ghr);
            float z  = sigmoidf_(gi[H + colj] + ghz);
            float n  = tanhf(gi[2 * H + colj] + rr * ghn);
            const size_t idx = (size_t)row * H + colj;
            float hnew = (1.0f - z) * n + z * h[idx];
            h[idx] = hnew;
            uintT u = __float_as_uint(hnew);
            const int rbl = wr * 2 + mi;
            const int inner = ((lane >> 4) * 4 + r) * 8 + innerB;
            eb[rbl * 1024 + inner] = (ushortT)(u >> 16);
            eb[rbl * 1024 + 512 + inner] =
                (ushortT)(__float_as_uint(hnew - __uint_as_float(u & 0xFFFF0000u)) >> 16);
        }
    }
    EPILOGUE_STORE(32)
}

// ===========================================================================
// FUSED decoder step: Hd = 2H, gates {j, 2H+j, 4H+j}. Same structure.
// ===========================================================================
__global__ __launch_bounds__(256) void fused_step_dec(
    const ushortT* __restrict__ Afr, const ushortT* __restrict__ Wfr,
    const float* __restrict__ giTabD, const int* __restrict__ tok,
    const float* __restrict__ bhD,
    float* __restrict__ h, ushortT* __restrict__ AfrOut)
{
    __shared__ ushortT sB[2][24 * 512];
    __shared__ int sTok[64];
    const int t = threadIdx.x, lane = t & 63, w = t >> 6;
    const int bid = blockIdx.x;
    const int xcd = bid & 7, q = bid >> 3;
    const int jg = xcd + 8 * (q & 7);     // [0,64)
    const int mb = q >> 3;                // [0,8)
    const int j0 = jg * 32, m0 = mb * 64;
    const int NCKd = 64, NP = 32;

    if (t < 64) sTok[t] = tok[m0 + t];

    const int wr = w >> 1, wc = w & 1;
    const ushortT* aP = Afr + (size_t)((m0 >> 4) + wr * 2) * (NCKd * 1024) + lane * 8;

    const ushortT* gWb[3];
    int lds0[3], lds1[3];
#pragma unroll
    for (int k = 0; k < 3; ++k) {
        int f = w * 3 + k;
        int jbLoc = f / 6, rem = f % 6;
        gWb[k] = Wfr + (size_t)(jg * 2 + jbLoc) * (NCKd * 3072) + rem * 512 + lane * 8;
        lds0[k] = f * 512 + lane * 8;
        lds1[k] = (12 + f) * 512 + lane * 8;
    }
    const int rb0 = wc * 3072 + lane * 8;

    floatx4 acc[2][3];
#pragma unroll
    for (int mi = 0; mi < 2; ++mi)
#pragma unroll
        for (int g = 0; g < 3; ++g) acc[mi][g] = (floatx4){0.f, 0.f, 0.f, 0.f};

    short8 aA[8], aB[8];
    uint4 bT[6];

    {
        uint4 p0[6];
#pragma unroll
        for (int k = 0; k < 3; ++k) {
            p0[k]     = *(const uint4*)(gWb[k]);
            p0[3 + k] = *(const uint4*)(gWb[k] + 3072);
        }
#pragma unroll
        for (int c = 0; c < 2; ++c) {
            const ushortT* ap_ = aP + (size_t)c * 1024;
            aA[c*4+0] = *(const short8*)(ap_);
            aA[c*4+1] = *(const short8*)(ap_ + 512);
            aA[c*4+2] = *(const short8*)(ap_ + NCKd * 1024);
            aA[c*4+3] = *(const short8*)(ap_ + NCKd * 1024 + 512);
        }
#pragma unroll
        for (int k = 0; k < 3; ++k) {
            *(uint4*)&sB[0][lds0[k]] = p0[k];
            *(uint4*)&sB[0][lds1[k]] = p0[3 + k];
        }
    }
    __syncthreads();

    for (int ip = 0; ip < NP; ip += 2) {
        PAIR_BODY(ip,     aA, aB, 0);
        PAIR_BODY(ip + 1, aB, aA, 1);
    }

    const int colj = j0 + wc * 16 + (lane & 15);
    const float bR = bhD[colj], bZ = bhD[H2 + colj], bN = bhD[2 * H2 + colj];
    const int rloc0 = wr * 32 + (lane >> 4) * 4;
    const int cA = j0 >> 5;
    const int innerB = ((colj >> 3) & 3) * 128 + (colj & 7);
    ushortT* eb = &sB[0][0];
#pragma unroll
    for (int mi = 0; mi < 2; ++mi) {
#pragma unroll
        for (int r = 0; r < 4; ++r) {
            const int rloc = rloc0 + mi * 16 + r;
            const int row = m0 + rloc;
            const float* gi = giTabD + (size_t)sTok[rloc] * H6;
            float ghr = acc[mi][0][r] + bR;
            float ghz = acc[mi][1][r] + bZ;
            float ghn = acc[mi][2][r] + bN;
            float rr = sigmoidf_(gi[colj] + ghr);
            float z  = sigmoidf_(gi[H2 + colj] + ghz);
            float n  = tanhf(gi[2 * H2 + colj] + rr * ghn);
            const size_t idx = (size_t)row * H2 + colj;
            float hnew = (1.0f - z) * n + z * h[idx];
            h[idx] = hnew;
            uintT u = __float_as_uint(hnew);
            const int rbl = wr * 2 + mi;
            const int inner = ((lane >> 4) * 4 + r) * 8 + innerB;
            eb[rbl * 1024 + inner] = (ushortT)(u >> 16);
            eb[rbl * 1024 + 512 + inner] =
                (ushortT)(__float_as_uint(hnew - __uint_as_float(u & 0xFFFF0000u)) >> 16);
        }
    }
    EPILOGUE_STORE(64)
}

// hh fp32 row-major + dec A planes (fragment-major); tok[b]=tgt[b,0]
__global__ __launch_bounds__(256) void init_hh_tok_split(
    const float* __restrict__ h_f, const float* __restrict__ h_b,
    const int* __restrict__ tgt, float* __restrict__ hh,
    ushortT* __restrict__ AfrD, int* __restrict__ tok)
{
    int i = blockIdx.x * blockDim.x + threadIdx.x;   // over B*2H
    int b = i >> 11;
    int j = i & 2047;
    float v = (j < H) ? h_f[(size_t)b * H + j] : h_b[(size_t)b * H + (j - H)];
    hh[i] = v;
    uintT u = __float_as_uint(v);
    size_t ao = (((size_t)(b >> 4) * 64 + (j >> 5)) * 2) * 512
              + (size_t)((b & 15) + 16 * ((j >> 3) & 3)) * 8 + (j & 7);
    AfrD[ao] = (ushortT)(u >> 16);
    AfrD[ao + 512] = (ushortT)(__float_as_uint(v - __uint_as_float(u & 0xFFFF0000u)) >> 16);
    if (j == 0) tok[b] = tgt[b * T];
}

// ===========================================================================
// logits = hh @ W_fc^T + b_fc (V=128) + argmax; 2 rows/block, 256 thr.
// ===========================================================================
__global__ __launch_bounds__(256) void logits_argmax2(
    const float* __restrict__ hh, const float* __restrict__ W_fc,
    const float* __restrict__ b_fc, float* __restrict__ out,
    int* __restrict__ tok, int t)
{
    __shared__ float sh[2][H2];
    __shared__ float sred[2][2][128];
    __shared__ float sval[2][128];
    __shared__ int   sidx[2][128];
    const int tid = threadIdx.x;
    const int col = tid & 127;
    const int kh  = tid >> 7;
    const int b0  = blockIdx.x * 2;

    {
        const float4* srcp = (const float4*)(hh + (size_t)b0 * H2);
        float4* dst = (float4*)sh;
        for (int i = tid; i < 2 * H2 / 4; i += 256) dst[i] = srcp[i];
    }
    __syncthreads();

    const float* wrow = W_fc + (size_t)col * H2 + kh * (H2 / 2);
    const float* s0 = sh[0] + kh * (H2 / 2);
    const float* s1 = sh[1] + kh * (H2 / 2);
    float a0 = 0.f, a1 = 0.f;
#pragma unroll 8
    for (int k = 0; k < H2 / 2; k += 4) {
        float4 w4 = *(const float4*)(wrow + k);
        float4 h0 = *(const float4*)(s0 + k);
        float4 h1 = *(const float4*)(s1 + k);
        a0 += w4.x * h0.x + w4.y * h0.y + w4.z * h0.z + w4.w * h0.w;
        a1 += w4.x * h1.x + w4.y * h1.y + w4.z * h1.z + w4.w * h1.w;
    }
    sred[kh][0][col] = a0;
    sred[kh][1][col] = a1;
    __syncthreads();

    if (kh == 0) {
        float l0 = sred[0][0][col] + sred[1][0][col] + b_fc[col];
        float l1 = sred[0][1][col] + sred[1][1][col] + b_fc[col];
        out[(size_t)(b0 + 0) * ((T - 1) * VOUTD) + (size_t)t * VOUTD + col] = l0;
        out[(size_t)(b0 + 1) * ((T - 1) * VOUTD) + (size_t)t * VOUTD + col] = l1;
        sval[0][col] = l0; sidx[0][col] = col;
        sval[1][col] = l1; sidx[1][col] = col;
    }
    __syncthreads();

    const int r = tid >> 7, c = tid & 127;
    for (int off = 64; off > 0; off >>= 1) {
        if (c < off) {
            float ov = sval[r][c + off]; int oi = sidx[r][c + off];
            if (ov > sval[r][c] || (ov == sval[r][c] && oi < sidx[r][c])) {
                sval[r][c] = ov; sidx[r][c] = oi;
            }
        }
        __syncthreads();
    }
    if (tid < 2) tok[b0 + tid] = sidx[tid][0];
}

// ===========================================================================
// Split-K fp32 GEMM (exact): Cp[z][128,N] = A[:, zKc:(z+1)Kc] @ W[:, ...]^T
// + deterministic combine (sum parts in k-order, then +bias).
// ===========================================================================
__global__ __launch_bounds__(256) void gemm_sk(
    const float* __restrict__ Abase, int lda,
    const float* __restrict__ W, float* __restrict__ Cp, int N, int K, int KS)
{
    __shared__ float As[16][68];
    __shared__ float Ws[16][68];
    const int t = threadIdx.x;
    const int m0 = blockIdx.y * 64, n0 = blockIdx.x * 64;
    const int Kc = K / KS, kb = blockIdx.z * Kc;
    const int lr = t >> 2, lc = (t & 3) << 2;
    const int tx = t & 15, ty = t >> 4;
    const int tn0 = tx << 2, tm0 = ty << 2;
    const float* Aptr = Abase + (size_t)(m0 + lr) * lda + kb;
    const float* Wptr = W + (size_t)(n0 + lr) * K + kb;
    float acc[4][4] = {{0.f}};
    for (int k0 = 0; k0 < Kc; k0 += 16) {
        float4 a4 = *(const float4*)(Aptr + k0 + lc);
        float4 w4 = *(const float4*)(Wptr + k0 + lc);
        __syncthreads();
        As[lc+0][lr] = a4.x; As[lc+1][lr] = a4.y; As[lc+2][lr] = a4.z; As[lc+3][lr] = a4.w;
        Ws[lc+0][lr] = w4.x; Ws[lc+1][lr] = w4.y; Ws[lc+2][lr] = w4.z; Ws[lc+3][lr] = w4.w;
        __syncthreads();
#pragma unroll
        for (int kk = 0; kk < 16; ++kk) {
            float4 av = *(const float4*)&As[kk][tm0];
            float4 wv = *(const float4*)&Ws[kk][tn0];
            float am[4] = {av.x, av.y, av.z, av.w};
            float wn[4] = {wv.x, wv.y, wv.z, wv.w};
#pragma unroll
            for (int i = 0; i < 4; ++i)
#pragma unroll
                for (int j = 0; j < 4; ++j) acc[i][j] += am[i] * wn[j];
        }
    }
    float* Cb = Cp + ((size_t)blockIdx.z * VOUTD + m0 + tm0) * N + n0 + tn0;
#pragma unroll
    for (int i = 0; i < 4; ++i)
        *(float4*)(Cb + (size_t)i * N) = make_float4(acc[i][0], acc[i][1], acc[i][2], acc[i][3]);
}

__global__ __launch_bounds__(256) void gi_combine(
    const float* __restrict__ Cp, const float* __restrict__ bias,
    float* __restrict__ Cout, int N, int KS)
{
    int j = blockIdx.x * 256 + threadIdx.x;
    int v = blockIdx.y;
    float s = 0.f;
    for (int z = 0; z < KS; ++z) s += Cp[((size_t)z * VOUTD + v) * N + j];
    Cout[(size_t)v * N + j] = s + bias[j];
}

// ===========================================================================
// fp32 vector GEMM (fallback path only).
// ===========================================================================
__global__ __launch_bounds__(256) void gemm_bias(
    const float* __restrict__ Abase,
    const int* __restrict__ idx, int idxStride, int idxOff, int lda,
    const float* __restrict__ W, const float* __restrict__ bias,
    float* __restrict__ C, int N, int K)
{
    __shared__ float As[16][68];
    __shared__ float Ws[16][68];
    const int t = threadIdx.x;
    const int m0 = blockIdx.y * 64, n0 = blockIdx.x * 64;
    const int lr = t >> 2, lc = (t & 3) << 2;
    const int tx = t & 15, ty = t >> 4;
    const int tn0 = tx << 2, tm0 = ty << 2;
    const int arow = m0 + lr;
    const float* Aptr = idx ? (Abase + (size_t)idx[arow * idxStride + idxOff] * lda)
                            : (Abase + (size_t)arow * lda);
    const float* Wptr = W + (size_t)(n0 + lr) * K;
    float acc[4][4] = {{0.f}};
    for (int k0 = 0; k0 < K; k0 += 16) {
        float4 a4 = *(const float4*)(Aptr + k0 + lc);
        float4 w4 = *(const float4*)(Wptr + k0 + lc);
        __syncthreads();
        As[lc+0][lr] = a4.x; As[lc+1][lr] = a4.y; As[lc+2][lr] = a4.z; As[lc+3][lr] = a4.w;
        Ws[lc+0][lr] = w4.x; Ws[lc+1][lr] = w4.y; Ws[lc+2][lr] = w4.z; Ws[lc+3][lr] = w4.w;
        __syncthreads();
#pragma unroll
        for (int kk = 0; kk < 16; ++kk) {
            float4 av = *(const float4*)&As[kk][tm0];
            float4 wv = *(const float4*)&Ws[kk][tn0];
            float am[4] = {av.x, av.y, av.z, av.w};
            float wn[4] = {wv.x, wv.y, wv.z, wv.w};
#pragma unroll
            for (int i = 0; i < 4; ++i)
#pragma unroll
                for (int j = 0; j < 4; ++j) acc[i][j] += am[i] * wn[j];
        }
    }
    const float b0 = bias[n0+tn0], b1 = bias[n0+tn0+1], b2 = bias[n0+tn0+2], b3 = bias[n0+tn0+3];
#pragma unroll
    for (int i = 0; i < 4; ++i) {
        float4 o = make_float4(acc[i][0]+b0, acc[i][1]+b1, acc[i][2]+b2, acc[i][3]+b3);
        *(float4*)(C + (size_t)(m0 + tm0 + i) * N + n0 + tn0) = o;
    }
}

__global__ __launch_bounds__(256) void gemm_enc(
    const float* __restrict__ Abase, int lda, int K,
    const int* __restrict__ srcIdx, int s,
    const float* __restrict__ W1, const float* __restrict__ bias1,
    const float* __restrict__ W2, const float* __restrict__ bias2,
    float* __restrict__ C, int N)
{
    __shared__ float As[16][68];
    __shared__ float Ws[16][68];
    const int t = threadIdx.x;
    const int m0 = blockIdx.y * 64, n0 = blockIdx.x * 64;
    const bool bwd = (m0 >= B);
    const float* W = bwd ? W2 : W1;
    const float* bias = bwd ? bias2 : bias1;
    const int lr = t >> 2, lc = (t & 3) << 2;
    const int tx = t & 15, ty = t >> 4;
    const int tn0 = tx << 2, tm0 = ty << 2;
    const int arow = m0 + lr;
    const float* Aptr;
    if (srcIdx) {
        int r = arow & (B - 1);
        int sidx = bwd ? (S - 1 - s) : s;
        Aptr = Abase + (size_t)srcIdx[r * S + sidx] * lda;
    } else Aptr = Abase + (size_t)arow * lda;
    const float* Wptr = W + (size_t)(n0 + lr) * K;
    float acc[4][4] = {{0.f}};
    for (int k0 = 0; k0 < K; k0 += 16) {
        float4 a4 = *(const float4*)(Aptr + k0 + lc);
        float4 w4 = *(const float4*)(Wptr + k0 + lc);
        __syncthreads();
        As[lc+0][lr] = a4.x; As[lc+1][lr] = a4.y; As[lc+2][lr] = a4.z; As[lc+3][lr] = a4.w;
        Ws[lc+0][lr] = w4.x; Ws[lc+1][lr] = w4.y; Ws[lc+2][lr] = w4.z; Ws[lc+3][lr] = w4.w;
        __syncthreads();
#pragma unroll
        for (int kk = 0; kk < 16; ++kk) {
            float4 av = *(const float4*)&As[kk][tm0];
            float4 wv = *(const float4*)&Ws[kk][tn0];
            float am[4] = {av.x, av.y, av.z, av.w};
            float wn[4] = {wv.x, wv.y, wv.z, wv.w};
#pragma unroll
            for (int i = 0; i < 4; ++i)
#pragma unroll
                for (int j = 0; j < 4; ++j) acc[i][j] += am[i] * wn[j];
        }
    }
    const float b0 = bias[n0+tn0], b1 = bias[n0+tn0+1], b2 = bias[n0+tn0+2], b3 = bias[n0+tn0+3];
#pragma unroll
    for (int i = 0; i < 4; ++i) {
        float4 o = make_float4(acc[i][0]+b0, acc[i][1]+b1, acc[i][2]+b2, acc[i][3]+b3);
        *(float4*)(C + (size_t)(m0 + tm0 + i) * N + n0 + tn0) = o;
    }
}

__global__ __launch_bounds__(256) void gru_gate(
    const float* __restrict__ gi, const float* __restrict__ gh,
    float* __restrict__ h, int Hd)
{
    int i = blockIdx.x * blockDim.x + threadIdx.x;
    int b = i / Hd, j = i - b * Hd;
    const float* gib = gi + (size_t)b * 3 * Hd;
    const float* ghb = gh + (size_t)b * 3 * Hd;
    float r = sigmoidf_(gib[j] + ghb[j]);
    float z = sigmoidf_(gib[Hd + j] + ghb[Hd + j]);
    float n = tanhf(gib[2 * Hd + j] + r * ghb[2 * Hd + j]);
    h[i] = (1.0f - z) * n + z * h[i];
}

__global__ __launch_bounds__(256) void init_hh_tok(
    const float* __restrict__ h_f, const float* __restrict__ h_b,
    const int* __restrict__ tgt, float* __restrict__ hh, int* __restrict__ tok)
{
    int i = blockIdx.x * blockDim.x + threadIdx.x;
    int b = i >> 11, j = i & 2047;
    hh[i] = (j < H) ? h_f[(size_t)b * H + j] : h_b[(size_t)b * H + (j - H)];
    if (j == 0) tok[b] = tgt[b * T];
}

// ===========================================================================
extern "C" void kernel_launch(void* const* d_in, const int* in_sizes, int n_in,
                              void* d_out, int out_size, void* d_ws, size_t ws_size,
                              hipStream_t stream)
{
    const int*   src     = (const int*)d_in[0];
    const int*   tgt     = (const int*)d_in[1];
    const float* enc_emb = (const float*)d_in[2];
    const float* dec_emb = (const float*)d_in[3];
    const float* W_ih_f  = (const float*)d_in[4];
    const float* W_hh_f  = (const float*)d_in[5];
    const float* b_ih_f  = (const float*)d_in[6];
    const float* b_hh_f  = (const float*)d_in[7];
    const float* W_ih_b  = (const float*)d_in[8];
    const float* W_hh_b  = (const float*)d_in[9];
    const float* b_ih_b  = (const float*)d_in[10];
    const float* b_hh_b  = (const float*)d_in[11];
    const float* W_ih_d  = (const float*)d_in[12];
    const float* W_hh_d  = (const float*)d_in[13];
    const float* b_ih_d  = (const float*)d_in[14];
    const float* b_hh_d  = (const float*)d_in[15];
    const float* W_fc    = (const float*)d_in[16];
    const float* b_fc    = (const float*)d_in[17];
    float* out = (float*)d_out;

    // ---------------- workspace layout ----------------
    char* base = (char*)d_ws;
    size_t off = 0;
    auto alloc = [&](size_t bytes) { char* p = base + off; off += (bytes + 255) & ~(size_t)255; return p; };

    float*   hE     = (float*)  alloc((size_t)2 * B * H * 4);       // zeroed with AfrEA
    ushortT* AfrEA  = (ushortT*)alloc((size_t)2 * B * H * 2 * 2);   // enc A planes ping
    ushortT* AfrEB  = (ushortT*)alloc((size_t)2 * B * H * 2 * 2);   // enc A planes pong
    float*   hh     = (float*)  alloc((size_t)B * H2 * 4);
    ushortT* AfrDA  = (ushortT*)alloc((size_t)B * H2 * 2 * 2);      // dec A planes ping
    ushortT* AfrDB  = (ushortT*)alloc((size_t)B * H2 * 2 * 2);      // dec A planes pong
    float*   giTabF = (float*)  alloc((size_t)VOUTD * H3 * 4);
    float*   giTabB = (float*)  alloc((size_t)VOUTD * H3 * 4);
    float*   giTabD = (float*)  alloc((size_t)VOUTD * H6 * 4);
    float*   giPart = (float*)  alloc((size_t)4 * VOUTD * H6 * 4);  // split-K partials
    ushortT* WfrF   = (ushortT*)alloc((size_t)H3 * H * 2 * 2);
    ushortT* WfrB   = (ushortT*)alloc((size_t)H3 * H * 2 * 2);
    ushortT* WfrD   = (ushortT*)alloc((size_t)H6 * H2 * 2 * 2);
    int*     tok    = (int*)    alloc((size_t)B * 4);
    size_t required = off;

    dim3 blk(256);

    if (ws_size >= required) {
        // =================== fragment-major fused path ===================
        {   // zero hE fp32 + AfrEA (contiguous)
            size_t zbytes = (size_t)2 * B * H * 4 + (size_t)2 * B * H * 4;
            int n16 = (int)(zbytes / 16);
            zero16<<<dim3((n16 + 255) / 256), blk, 0, stream>>>((uint4*)hE, n16);
        }
        // W -> fragment-major hi/lo (coalesced, wave per fragment)
        {
            int fe = (H / 16) * (H / 32) * 3;        // 6144
            int fd = (H2 / 16) * (H2 / 32) * 3;      // 24576
            swizzle_w<<<dim3((fe + 3) / 4), blk, 0, stream>>>(W_hh_f, WfrF, 10, 7);
            swizzle_w<<<dim3((fe + 3) / 4), blk, 0, stream>>>(W_hh_b, WfrB, 10, 7);
            swizzle_w<<<dim3((fd + 3) / 4), blk, 0, stream>>>(W_hh_d, WfrD, 11, 8);
        }

        // gi tables (exact fp32, split-K x4)
        gemm_sk<<<dim3(H3 / 64, VOUTD / 64, 4), blk, 0, stream>>>(
            enc_emb, E, W_ih_f, giPart, H3, E, 4);
        gi_combine<<<dim3(H3 / 256, VOUTD), blk, 0, stream>>>(giPart, b_ih_f, giTabF, H3, 4);
        gemm_sk<<<dim3(H3 / 64, VOUTD / 64, 4), blk, 0, stream>>>(
            enc_emb, E, W_ih_b, giPart, H3, E, 4);
        gi_combine<<<dim3(H3 / 256, VOUTD), blk, 0, stream>>>(giPart, b_ih_b, giTabB, H3, 4);
        gemm_sk<<<dim3(H6 / 64, VOUTD / 64, 4), blk, 0, stream>>>(
            dec_emb, E, W_ih_d, giPart, H6, E, 4);
        gi_combine<<<dim3(H6 / 256, VOUTD), blk, 0, stream>>>(giPart, b_ih_d, giTabD, H6, 4);

        // ---------------- Encoder: 64 fused steps ----------------
        for (int s = 0; s < S; ++s) {
            const ushortT* inA = (s & 1) ? AfrEB : AfrEA;
            ushortT* outA = (s & 1) ? AfrEA : AfrEB;
            fused_step_enc<<<dim3(512), blk, 0, stream>>>(
                inA, WfrF, WfrB, giTabF, giTabB, src, s, b_hh_f, b_hh_b, hE, outA);
        }

        init_hh_tok_split<<<dim3((B * H2) / 256), blk, 0, stream>>>(
            hE, hE + (size_t)B * H, tgt, hh, AfrDA, tok);

        // ---------------- Decoder: 31 fused steps ----------------
        for (int t = 0; t < T - 1; ++t) {
            const ushortT* inA = (t & 1) ? AfrDB : AfrDA;
            ushortT* outA = (t & 1) ? AfrDA : AfrDB;
            fused_step_dec<<<dim3(512), blk, 0, stream>>>(
                inA, WfrD, giTabD, tok, b_hh_d, hh, outA);
            logits_argmax2<<<dim3(B / 2), blk, 0, stream>>>(hh, W_fc, b_fc, out, tok, t);
        }
    } else {
        // =================== fp32 fallback (R1-proven path) ===================
        {
            size_t zbytes = (size_t)2 * B * H * 4;
            int n16 = (int)(zbytes / 16);
            zero16<<<dim3((n16 + 255) / 256), blk, 0, stream>>>((uint4*)hE, n16);
        }
        float* giE = (float*)WfrF;                       // scratch overlay
        float* ghF = giE + (size_t)2 * B * H3;
        dim3 grid_gi(H3 / 64, (2 * B) / 64);
        dim3 grid_gate((2 * B * H) / 256);
        for (int s = 0; s < S; ++s) {
            gemm_enc<<<grid_gi, blk, 0, stream>>>(enc_emb, E, E, src, s,
                                                  W_ih_f, b_ih_f, W_ih_b, b_ih_b, giE, H3);
            gemm_enc<<<grid_gi, blk, 0, stream>>>(hE, H, H, nullptr, 0,
                                                  W_hh_f, b_hh_f, W_hh_b, b_hh_b, ghF, H3);
            gru_gate<<<grid_gate, blk, 0, stream>>>(giE, ghF, hE, H);
        }
        init_hh_tok<<<dim3((B * H2) / 256), blk, 0, stream>>>(hE, hE + (size_t)B * H, tgt, hh, tok);
        dim3 grid_d(H6 / 64, B / 64);
        dim3 grid_dgate((B * H2) / 256);
        for (int t = 0; t < T - 1; ++t) {
            gemm_bias<<<grid_d, blk, 0, stream>>>(dec_emb, tok, 1, 0, E,
                                                  W_ih_d, b_ih_d, giE, H6, E);
            gemm_bias<<<grid_d, blk, 0, stream>>>(hh, nullptr, 0, 0, H2,
                                                  W_hh_d, b_hh_d, ghF, H6, H2);
            gru_gate<<<grid_dgate, blk, 0, stream>>>(giE, ghF, hh, H2);
            logits_argmax2<<<dim3(B / 2), blk, 0, stream>>>(hh, W_fc, b_fc, out, tok, t);
        }
    }
}

// Round 7
// 4932.284 us; speedup vs baseline: 1.9959x; 1.7028x over previous
//
#include <hip/hip_runtime.h>
#include <math.h>

#define B 512
#define S 64
#define T 32
#define E 512
#define H 1024
#define VOUTD 128
#define H2 (2*H)
#define H3 (3*H)
#define H6 (6*H)

typedef unsigned short ushortT;
typedef unsigned int uintT;
typedef __attribute__((ext_vector_type(8))) short short8;
typedef __attribute__((ext_vector_type(4))) float floatx4;

__device__ __forceinline__ float sigmoidf_(float x) { return 1.0f / (1.0f + expf(-x)); }

__device__ __forceinline__ uintT pack_hi2(float a, float b) {
    return (__float_as_uint(a) >> 16) | (__float_as_uint(b) & 0xFFFF0000u);
}
__device__ __forceinline__ uintT pack_lo2(float a, float b) {
    uintT ua = __float_as_uint(a), ub = __float_as_uint(b);
    uintT la = __float_as_uint(a - __uint_as_float(ua & 0xFFFF0000u)) >> 16;
    uintT lb = __float_as_uint(b - __uint_as_float(ub & 0xFFFF0000u)) >> 16;
    return la | (lb << 16);
}

__global__ __launch_bounds__(256) void zero16(uint4* __restrict__ p, int n)
{
    int i = blockIdx.x * 256 + threadIdx.x;
    if (i < n) p[i] = make_uint4(0u, 0u, 0u, 0u);
}

// ===========================================================================
// W -> fragment-major hi/lo planes. COALESCED: one wave per fragment.
// Fragment f = (jb*ncK + c)*3 + g; 1024 shorts (hi 512 | lo 512).
// Lane l: jl=l&15, kq=l>>4 reads W[g*nj + jb*16 + jl][c*32 + kq*8 .. +8)
// and writes out[f*1024 + l*8] (hi) and +512 (lo): contiguous 1KB per wave.
// ncK = K/32 = 1 << (kShift-2)  =>  jb = rest >> (kShift-2).
// ===========================================================================
__global__ __launch_bounds__(256) void swizzle_w(
    const float* __restrict__ W, ushortT* __restrict__ out, int njShift, int kShift)
{
    const int K = 8 << kShift;
    const int nj = 1 << njShift;
    const int ncK = K >> 5;
    const int total = (nj >> 4) * ncK * 3;
    int f = blockIdx.x * 4 + (threadIdx.x >> 6);
    if (f >= total) return;
    const int lane = threadIdx.x & 63;
    int g = f % 3;
    int rest = f / 3;
    int c = rest & (ncK - 1);
    int jb = rest >> (kShift - 2);
    int jl = lane & 15, kq = lane >> 4;
    int row = g * nj + jb * 16 + jl;
    int k = c * 32 + kq * 8;
    const float* s = W + (size_t)row * K + k;
    float4 f0 = *(const float4*)s;
    float4 f1 = *(const float4*)(s + 4);
    uint4 hv = make_uint4(pack_hi2(f0.x, f0.y), pack_hi2(f0.z, f0.w),
                          pack_hi2(f1.x, f1.y), pack_hi2(f1.z, f1.w));
    uint4 lv = make_uint4(pack_lo2(f0.x, f0.y), pack_lo2(f0.z, f0.w),
                          pack_lo2(f1.x, f1.y), pack_lo2(f1.z, f1.w));
    size_t base = (size_t)f * 1024 + (size_t)lane * 8;
    *(uint4*)(out + base) = hv;
    *(uint4*)(out + base + 512) = lv;
}

// ===========================================================================
// Barrier-free streaming main loop: each wave reads ITS OWN B fragments
// (jb-half = wc) and A row-frags (wr) straight global->register. No LDS,
// no __syncthreads in the loop -> compiler emits counted vmcnt per use,
// waves slip freely, HBM stays continuously busy. 2-deep reg ping-pong.
// MFMA order per acc: Ah*Bh, Ah*Bl, Al*Bh; chunks ascending (bit-identical
// to the R3/R6 numerics).
// ===========================================================================
#define MFMA16(a, b, c) __builtin_amdgcn_mfma_f32_16x16x32_bf16(a, b, c, 0, 0, 0)

#define LOADSET(SET, C)                                                         \
    {                                                                           \
        const ushortT* bp_ = bPtr + (size_t)(C) * 3072;                         \
        SET##b[0] = *(const short8*)(bp_);                                      \
        SET##b[1] = *(const short8*)(bp_ + 512);                                \
        SET##b[2] = *(const short8*)(bp_ + 1024);                               \
        SET##b[3] = *(const short8*)(bp_ + 1536);                               \
        SET##b[4] = *(const short8*)(bp_ + 2048);                               \
        SET##b[5] = *(const short8*)(bp_ + 2560);                               \
        const ushortT* ap_ = aPtr + (size_t)(C) * 1024;                         \
        SET##a[0] = *(const short8*)(ap_);                                      \
        SET##a[1] = *(const short8*)(ap_ + 512);                                \
        SET##a[2] = *(const short8*)(ap_ + NCKd * 1024);                        \
        SET##a[3] = *(const short8*)(ap_ + NCKd * 1024 + 512);                  \
    }

#define COMPSET(SET)                                                            \
    _Pragma("unroll")                                                           \
    for (int g = 0; g < 3; ++g) {                                               \
        short8 bh_ = SET##b[g * 2], bl_ = SET##b[g * 2 + 1];                    \
        acc[0][g] = MFMA16(SET##a[0], bh_, acc[0][g]);                          \
        acc[0][g] = MFMA16(SET##a[0], bl_, acc[0][g]);                          \
        acc[0][g] = MFMA16(SET##a[1], bh_, acc[0][g]);                          \
        acc[1][g] = MFMA16(SET##a[2], bh_, acc[1][g]);                          \
        acc[1][g] = MFMA16(SET##a[2], bl_, acc[1][g]);                          \
        acc[1][g] = MFMA16(SET##a[3], bh_, acc[1][g]);                          \
    }

// Coalesced fragment-plane epilogue: stage packed shorts in LDS, one
// barrier, stream out 8KB contiguous (2 uint4/thread).
#define EPILOGUE_STORE(NCKA)                                                    \
    __syncthreads();                                                            \
    _Pragma("unroll")                                                           \
    for (int v = 0; v < 2; ++v) {                                               \
        int idx = t * 2 + v;                                                    \
        int rbo = idx >> 7;                                                     \
        int offs = (idx & 127) * 8;                                             \
        size_t gbase = ((size_t)((m0 >> 4) + rbo) * (NCKA) + cA) * 1024;        \
        *(uint4*)(AfrOut + gbase + offs) = *(const uint4*)&eb[rbo * 1024 + offs]; \
    }

// ===========================================================================
// FUSED encoder step. Block: 64 rows x 32 j, 4 waves (2x2). Barrier-free.
// ===========================================================================
__global__ __launch_bounds__(256) void fused_step_enc(
    const ushortT* __restrict__ Afr,
    const ushortT* __restrict__ WfrF, const ushortT* __restrict__ WfrB,
    const float* __restrict__ giTabF, const float* __restrict__ giTabB,
    const int* __restrict__ src, int s,
    const float* __restrict__ bhF, const float* __restrict__ bhB,
    float* __restrict__ h, ushortT* __restrict__ AfrOut)
{
    __shared__ ushortT eb[4096];          // 8 KB epilogue staging
    const int t = threadIdx.x, lane = t & 63, w = t >> 6;
    const int bid = blockIdx.x;
    const int xcd = bid & 7, q = bid >> 3;
    const int jg = xcd + 8 * (q & 3);     // [0,32)
    const int mb = q >> 2;                // [0,16)
    const int j0 = jg * 32, m0 = mb * 64;
    const bool bwd = (m0 >= B);
    const ushortT* Wfr = bwd ? WfrB : WfrF;
    const float* giTab = bwd ? giTabB : giTabF;
    const float* bh = bwd ? bhB : bhF;
    const int NCKd = 32;
    const int sidx = bwd ? (S - 1 - s) : s;

    const int wr = w >> 1, wc = w & 1;
    const ushortT* aPtr = Afr + (size_t)((m0 >> 4) + wr * 2) * (NCKd * 1024) + lane * 8;
    const ushortT* bPtr = Wfr + (size_t)(jg * 2 + wc) * (NCKd * 3072) + lane * 8;

    floatx4 acc[2][3];
#pragma unroll
    for (int mi = 0; mi < 2; ++mi)
#pragma unroll
        for (int g = 0; g < 3; ++g) acc[mi][g] = (floatx4){0.f, 0.f, 0.f, 0.f};

    short8 s0b[6], s0a[4], s1b[6], s1a[4];
    LOADSET(s0, 0);
    for (int c = 0; c < NCKd; c += 2) {
        LOADSET(s1, c + 1);
        COMPSET(s0);
        if (c + 2 < NCKd) LOADSET(s0, c + 2);
        COMPSET(s1);
    }

    // fused gate epilogue: h fp32 RMW + packed bf16 planes staged to LDS.
    const int colj = j0 + wc * 16 + (lane & 15);
    const float bR = bh[colj], bZ = bh[H + colj], bN = bh[2 * H + colj];
    const int rloc0 = wr * 32 + (lane >> 4) * 4;
    const int cA = j0 >> 5;
    const int innerB = ((colj >> 3) & 3) * 128 + (colj & 7);
#pragma unroll
    for (int mi = 0; mi < 2; ++mi) {
#pragma unroll
        for (int r = 0; r < 4; ++r) {
            const int rloc = rloc0 + mi * 16 + r;
            const int row = m0 + rloc;
            const int tk = src[(row & (B - 1)) * S + sidx];
            const float* gi = giTab + (size_t)tk * H3;
            float ghr = acc[mi][0][r] + bR;
            float ghz = acc[mi][1][r] + bZ;
            float ghn = acc[mi][2][r] + bN;
            float rr = sigmoidf_(gi[colj] + ghr);
            float z  = sigmoidf_(gi[H + colj] + ghz);
            float n  = tanhf(gi[2 * H + colj] + rr * ghn);
            const size_t idx = (size_t)row * H + colj;
            float hnew = (1.0f - z) * n + z * h[idx];
            h[idx] = hnew;
            uintT u = __float_as_uint(hnew);
            const int rbl = wr * 2 + mi;
            const int inner = ((lane >> 4) * 4 + r) * 8 + innerB;
            eb[rbl * 1024 + inner] = (ushortT)(u >> 16);
            eb[rbl * 1024 + 512 + inner] =
                (ushortT)(__float_as_uint(hnew - __uint_as_float(u & 0xFFFF0000u)) >> 16);
        }
    }
    EPILOGUE_STORE(32)
}

// ===========================================================================
// FUSED decoder step: Hd = 2H, gates {j, 2H+j, 4H+j}. Barrier-free.
// ===========================================================================
__global__ __launch_bounds__(256) void fused_step_dec(
    const ushortT* __restrict__ Afr, const ushortT* __restrict__ Wfr,
    const float* __restrict__ giTabD, const int* __restrict__ tok,
    const float* __restrict__ bhD,
    float* __restrict__ h, ushortT* __restrict__ AfrOut)
{
    __shared__ ushortT eb[4096];
    const int t = threadIdx.x, lane = t & 63, w = t >> 6;
    const int bid = blockIdx.x;
    const int xcd = bid & 7, q = bid >> 3;
    const int jg = xcd + 8 * (q & 7);     // [0,64)
    const int mb = q >> 3;                // [0,8)
    const int j0 = jg * 32, m0 = mb * 64;
    const int NCKd = 64;

    const int wr = w >> 1, wc = w & 1;
    const ushortT* aPtr = Afr + (size_t)((m0 >> 4) + wr * 2) * (NCKd * 1024) + lane * 8;
    const ushortT* bPtr = Wfr + (size_t)(jg * 2 + wc) * (NCKd * 3072) + lane * 8;

    floatx4 acc[2][3];
#pragma unroll
    for (int mi = 0; mi < 2; ++mi)
#pragma unroll
        for (int g = 0; g < 3; ++g) acc[mi][g] = (floatx4){0.f, 0.f, 0.f, 0.f};

    short8 s0b[6], s0a[4], s1b[6], s1a[4];
    LOADSET(s0, 0);
    for (int c = 0; c < NCKd; c += 2) {
        LOADSET(s1, c + 1);
        COMPSET(s0);
        if (c + 2 < NCKd) LOADSET(s0, c + 2);
        COMPSET(s1);
    }

    const int colj = j0 + wc * 16 + (lane & 15);
    const float bR = bhD[colj], bZ = bhD[H2 + colj], bN = bhD[2 * H2 + colj];
    const int rloc0 = wr * 32 + (lane >> 4) * 4;
    const int cA = j0 >> 5;
    const int innerB = ((colj >> 3) & 3) * 128 + (colj & 7);
#pragma unroll
    for (int mi = 0; mi < 2; ++mi) {
#pragma unroll
        for (int r = 0; r < 4; ++r) {
            const int rloc = rloc0 + mi * 16 + r;
            const int row = m0 + rloc;
            const float* gi = giTabD + (size_t)tok[row] * H6;
            float ghr = acc[mi][0][r] + bR;
            float ghz = acc[mi][1][r] + bZ;
            float ghn = acc[mi][2][r] + bN;
            float rr = sigmoidf_(gi[colj] + ghr);
            float z  = sigmoidf_(gi[H2 + colj] + ghz);
            float n  = tanhf(gi[2 * H2 + colj] + rr * ghn);
            const size_t idx = (size_t)row * H2 + colj;
            float hnew = (1.0f - z) * n + z * h[idx];
            h[idx] = hnew;
            uintT u = __float_as_uint(hnew);
            const int rbl = wr * 2 + mi;
            const int inner = ((lane >> 4) * 4 + r) * 8 + innerB;
            eb[rbl * 1024 + inner] = (ushortT)(u >> 16);
            eb[rbl * 1024 + 512 + inner] =
                (ushortT)(__float_as_uint(hnew - __uint_as_float(u & 0xFFFF0000u)) >> 16);
        }
    }
    EPILOGUE_STORE(64)
}

// hh fp32 row-major + dec A planes (fragment-major); tok[b]=tgt[b,0]
__global__ __launch_bounds__(256) void init_hh_tok_split(
    const float* __restrict__ h_f, const float* __restrict__ h_b,
    const int* __restrict__ tgt, float* __restrict__ hh,
    ushortT* __restrict__ AfrD, int* __restrict__ tok)
{
    int i = blockIdx.x * blockDim.x + threadIdx.x;   // over B*2H
    int b = i >> 11;
    int j = i & 2047;
    float v = (j < H) ? h_f[(size_t)b * H + j] : h_b[(size_t)b * H + (j - H)];
    hh[i] = v;
    uintT u = __float_as_uint(v);
    size_t ao = (((size_t)(b >> 4) * 64 + (j >> 5)) * 2) * 512
              + (size_t)((b & 15) + 16 * ((j >> 3) & 3)) * 8 + (j & 7);
    AfrD[ao] = (ushortT)(u >> 16);
    AfrD[ao + 512] = (ushortT)(__float_as_uint(v - __uint_as_float(u & 0xFFFF0000u)) >> 16);
    if (j == 0) tok[b] = tgt[b * T];
}

// ===========================================================================
// logits = hh @ W_fc^T + b_fc (V=128) + argmax; 2 rows/block, 256 thr.
// ===========================================================================
__global__ __launch_bounds__(256) void logits_argmax2(
    const float* __restrict__ hh, const float* __restrict__ W_fc,
    const float* __restrict__ b_fc, float* __restrict__ out,
    int* __restrict__ tok, int t)
{
    __shared__ float sh[2][H2];
    __shared__ float sred[2][2][128];
    __shared__ float sval[2][128];
    __shared__ int   sidx[2][128];
    const int tid = threadIdx.x;
    const int col = tid & 127;
    const int kh  = tid >> 7;
    const int b0  = blockIdx.x * 2;

    {
        const float4* srcp = (const float4*)(hh + (size_t)b0 * H2);
        float4* dst = (float4*)sh;
        for (int i = tid; i < 2 * H2 / 4; i += 256) dst[i] = srcp[i];
    }
    __syncthreads();

    const float* wrow = W_fc + (size_t)col * H2 + kh * (H2 / 2);
    const float* s0 = sh[0] + kh * (H2 / 2);
    const float* s1 = sh[1] + kh * (H2 / 2);
    float a0 = 0.f, a1 = 0.f;
#pragma unroll 8
    for (int k = 0; k < H2 / 2; k += 4) {
        float4 w4 = *(const float4*)(wrow + k);
        float4 h0 = *(const float4*)(s0 + k);
        float4 h1 = *(const float4*)(s1 + k);
        a0 += w4.x * h0.x + w4.y * h0.y + w4.z * h0.z + w4.w * h0.w;
        a1 += w4.x * h1.x + w4.y * h1.y + w4.z * h1.z + w4.w * h1.w;
    }
    sred[kh][0][col] = a0;
    sred[kh][1][col] = a1;
    __syncthreads();

    if (kh == 0) {
        float l0 = sred[0][0][col] + sred[1][0][col] + b_fc[col];
        float l1 = sred[0][1][col] + sred[1][1][col] + b_fc[col];
        out[(size_t)(b0 + 0) * ((T - 1) * VOUTD) + (size_t)t * VOUTD + col] = l0;
        out[(size_t)(b0 + 1) * ((T - 1) * VOUTD) + (size_t)t * VOUTD + col] = l1;
        sval[0][col] = l0; sidx[0][col] = col;
        sval[1][col] = l1; sidx[1][col] = col;
    }
    __syncthreads();

    const int r = tid >> 7, c = tid & 127;
    for (int off = 64; off > 0; off >>= 1) {
        if (c < off) {
            float ov = sval[r][c + off]; int oi = sidx[r][c + off];
            if (ov > sval[r][c] || (ov == sval[r][c] && oi < sidx[r][c])) {
                sval[r][c] = ov; sidx[r][c] = oi;
            }
        }
        __syncthreads();
    }
    if (tid < 2) tok[b0 + tid] = sidx[tid][0];
}

// ===========================================================================
// Split-K fp32 GEMM (exact): Cp[z][128,N] = A[:, zKc:(z+1)Kc] @ W[:, ...]^T
// + deterministic combine (sum parts in k-order, then +bias).
// ===========================================================================
__global__ __launch_bounds__(256) void gemm_sk(
    const float* __restrict__ Abase, int lda,
    const float* __restrict__ W, float* __restrict__ Cp, int N, int K, int KS)
{
    __shared__ float As[16][68];
    __shared__ float Ws[16][68];
    const int t = threadIdx.x;
    const int m0 = blockIdx.y * 64, n0 = blockIdx.x * 64;
    const int Kc = K / KS, kb = blockIdx.z * Kc;
    const int lr = t >> 2, lc = (t & 3) << 2;
    const int tx = t & 15, ty = t >> 4;
    const int tn0 = tx << 2, tm0 = ty << 2;
    const float* Aptr = Abase + (size_t)(m0 + lr) * lda + kb;
    const float* Wptr = W + (size_t)(n0 + lr) * K + kb;
    float acc[4][4] = {{0.f}};
    for (int k0 = 0; k0 < Kc; k0 += 16) {
        float4 a4 = *(const float4*)(Aptr + k0 + lc);
        float4 w4 = *(const float4*)(Wptr + k0 + lc);
        __syncthreads();
        As[lc+0][lr] = a4.x; As[lc+1][lr] = a4.y; As[lc+2][lr] = a4.z; As[lc+3][lr] = a4.w;
        Ws[lc+0][lr] = w4.x; Ws[lc+1][lr] = w4.y; Ws[lc+2][lr] = w4.z; Ws[lc+3][lr] = w4.w;
        __syncthreads();
#pragma unroll
        for (int kk = 0; kk < 16; ++kk) {
            float4 av = *(const float4*)&As[kk][tm0];
            float4 wv = *(const float4*)&Ws[kk][tn0];
            float am[4] = {av.x, av.y, av.z, av.w};
            float wn[4] = {wv.x, wv.y, wv.z, wv.w};
#pragma unroll
            for (int i = 0; i < 4; ++i)
#pragma unroll
                for (int j = 0; j < 4; ++j) acc[i][j] += am[i] * wn[j];
        }
    }
    float* Cb = Cp + ((size_t)blockIdx.z * VOUTD + m0 + tm0) * N + n0 + tn0;
#pragma unroll
    for (int i = 0; i < 4; ++i)
        *(float4*)(Cb + (size_t)i * N) = make_float4(acc[i][0], acc[i][1], acc[i][2], acc[i][3]);
}

__global__ __launch_bounds__(256) void gi_combine(
    const float* __restrict__ Cp, const float* __restrict__ bias,
    float* __restrict__ Cout, int N, int KS)
{
    int j = blockIdx.x * 256 + threadIdx.x;
    int v = blockIdx.y;
    float s = 0.f;
    for (int z = 0; z < KS; ++z) s += Cp[((size_t)z * VOUTD + v) * N + j];
    Cout[(size_t)v * N + j] = s + bias[j];
}

// ===========================================================================
// fp32 vector GEMM (fallback path only).
// ===========================================================================
__global__ __launch_bounds__(256) void gemm_bias(
    const float* __restrict__ Abase,
    const int* __restrict__ idx, int idxStride, int idxOff, int lda,
    const float* __restrict__ W, const float* __restrict__ bias,
    float* __restrict__ C, int N, int K)
{
    __shared__ float As[16][68];
    __shared__ float Ws[16][68];
    const int t = threadIdx.x;
    const int m0 = blockIdx.y * 64, n0 = blockIdx.x * 64;
    const int lr = t >> 2, lc = (t & 3) << 2;
    const int tx = t & 15, ty = t >> 4;
    const int tn0 = tx << 2, tm0 = ty << 2;
    const int arow = m0 + lr;
    const float* Aptr = idx ? (Abase + (size_t)idx[arow * idxStride + idxOff] * lda)
                            : (Abase + (size_t)arow * lda);
    const float* Wptr = W + (size_t)(n0 + lr) * K;
    float acc[4][4] = {{0.f}};
    for (int k0 = 0; k0 < K; k0 += 16) {
        float4 a4 = *(const float4*)(Aptr + k0 + lc);
        float4 w4 = *(const float4*)(Wptr + k0 + lc);
        __syncthreads();
        As[lc+0][lr] = a4.x; As[lc+1][lr] = a4.y; As[lc+2][lr] = a4.z; As[lc+3][lr] = a4.w;
        Ws[lc+0][lr] = w4.x; Ws[lc+1][lr] = w4.y; Ws[lc+2][lr] = w4.z; Ws[lc+3][lr] = w4.w;
        __syncthreads();
#pragma unroll
        for (int kk = 0; kk < 16; ++kk) {
            float4 av = *(const float4*)&As[kk][tm0];
            float4 wv = *(const float4*)&Ws[kk][tn0];
            float am[4] = {av.x, av.y, av.z, av.w};
            float wn[4] = {wv.x, wv.y, wv.z, wv.w};
#pragma unroll
            for (int i = 0; i < 4; ++i)
#pragma unroll
                for (int j = 0; j < 4; ++j) acc[i][j] += am[i] * wn[j];
        }
    }
    const float b0 = bias[n0+tn0], b1 = bias[n0+tn0+1], b2 = bias[n0+tn0+2], b3 = bias[n0+tn0+3];
#pragma unroll
    for (int i = 0; i < 4; ++i) {
        float4 o = make_float4(acc[i][0]+b0, acc[i][1]+b1, acc[i][2]+b2, acc[i][3]+b3);
        *(float4*)(C + (size_t)(m0 + tm0 + i) * N + n0 + tn0) = o;
    }
}

__global__ __launch_bounds__(256) void gemm_enc(
    const float* __restrict__ Abase, int lda, int K,
    const int* __restrict__ srcIdx, int s,
    const float* __restrict__ W1, const float* __restrict__ bias1,
    const float* __restrict__ W2, const float* __restrict__ bias2,
    float* __restrict__ C, int N)
{
    __shared__ float As[16][68];
    __shared__ float Ws[16][68];
    const int t = threadIdx.x;
    const int m0 = blockIdx.y * 64, n0 = blockIdx.x * 64;
    const bool bwd = (m0 >= B);
    const float* W = bwd ? W2 : W1;
    const float* bias = bwd ? bias2 : bias1;
    const int lr = t >> 2, lc = (t & 3) << 2;
    const int tx = t & 15, ty = t >> 4;
    const int tn0 = tx << 2, tm0 = ty << 2;
    const int arow = m0 + lr;
    const float* Aptr;
    if (srcIdx) {
        int r = arow & (B - 1);
        int sidx = bwd ? (S - 1 - s) : s;
        Aptr = Abase + (size_t)srcIdx[r * S + sidx] * lda;
    } else Aptr = Abase + (size_t)arow * lda;
    const float* Wptr = W + (size_t)(n0 + lr) * K;
    float acc[4][4] = {{0.f}};
    for (int k0 = 0; k0 < K; k0 += 16) {
        float4 a4 = *(const float4*)(Aptr + k0 + lc);
        float4 w4 = *(const float4*)(Wptr + k0 + lc);
        __syncthreads();
        As[lc+0][lr] = a4.x; As[lc+1][lr] = a4.y; As[lc+2][lr] = a4.z; As[lc+3][lr] = a4.w;
        Ws[lc+0][lr] = w4.x; Ws[lc+1][lr] = w4.y; Ws[lc+2][lr] = w4.z; Ws[lc+3][lr] = w4.w;
        __syncthreads();
#pragma unroll
        for (int kk = 0; kk < 16; ++kk) {
            float4 av = *(const float4*)&As[kk][tm0];
            float4 wv = *(const float4*)&Ws[kk][tn0];
            float am[4] = {av.x, av.y, av.z, av.w};
            float wn[4] = {wv.x, wv.y, wv.z, wv.w};
#pragma unroll
            for (int i = 0; i < 4; ++i)
#pragma unroll
                for (int j = 0; j < 4; ++j) acc[i][j] += am[i] * wn[j];
        }
    }
    const float b0 = bias[n0+tn0], b1 = bias[n0+tn0+1], b2 = bias[n0+tn0+2], b3 = bias[n0+tn0+3];
#pragma unroll
    for (int i = 0; i < 4; ++i) {
        float4 o = make_float4(acc[i][0]+b0, acc[i][1]+b1, acc[i][2]+b2, acc[i][3]+b3);
        *(float4*)(C + (size_t)(m0 + tm0 + i) * N + n0 + tn0) = o;
    }
}

__global__ __launch_bounds__(256) void gru_gate(
    const float* __restrict__ gi, const float* __restrict__ gh,
    float* __restrict__ h, int Hd)
{
    int i = blockIdx.x * blockDim.x + threadIdx.x;
    int b = i / Hd, j = i - b * Hd;
    const float* gib = gi + (size_t)b * 3 * Hd;
    const float* ghb = gh + (size_t)b * 3 * Hd;
    float r = sigmoidf_(gib[j] + ghb[j]);
    float z = sigmoidf_(gib[Hd + j] + ghb[Hd + j]);
    float n = tanhf(gib[2 * Hd + j] + r * ghb[2 * Hd + j]);
    h[i] = (1.0f - z) * n + z * h[i];
}

__global__ __launch_bounds__(256) void init_hh_tok(
    const float* __restrict__ h_f, const float* __restrict__ h_b,
    const int* __restrict__ tgt, float* __restrict__ hh, int* __restrict__ tok)
{
    int i = blockIdx.x * blockDim.x + threadIdx.x;
    int b = i >> 11, j = i & 2047;
    hh[i] = (j < H) ? h_f[(size_t)b * H + j] : h_b[(size_t)b * H + (j - H)];
    if (j == 0) tok[b] = tgt[b * T];
}

// ===========================================================================
extern "C" void kernel_launch(void* const* d_in, const int* in_sizes, int n_in,
                              void* d_out, int out_size, void* d_ws, size_t ws_size,
                              hipStream_t stream)
{
    const int*   src     = (const int*)d_in[0];
    const int*   tgt     = (const int*)d_in[1];
    const float* enc_emb = (const float*)d_in[2];
    const float* dec_emb = (const float*)d_in[3];
    const float* W_ih_f  = (const float*)d_in[4];
    const float* W_hh_f  = (const float*)d_in[5];
    const float* b_ih_f  = (const float*)d_in[6];
    const float* b_hh_f  = (const float*)d_in[7];
    const float* W_ih_b  = (const float*)d_in[8];
    const float* W_hh_b  = (const float*)d_in[9];
    const float* b_ih_b  = (const float*)d_in[10];
    const float* b_hh_b  = (const float*)d_in[11];
    const float* W_ih_d  = (const float*)d_in[12];
    const float* W_hh_d  = (const float*)d_in[13];
    const float* b_ih_d  = (const float*)d_in[14];
    const float* b_hh_d  = (const float*)d_in[15];
    const float* W_fc    = (const float*)d_in[16];
    const float* b_fc    = (const float*)d_in[17];
    float* out = (float*)d_out;

    // ---------------- workspace layout ----------------
    char* base = (char*)d_ws;
    size_t off = 0;
    auto alloc = [&](size_t bytes) { char* p = base + off; off += (bytes + 255) & ~(size_t)255; return p; };

    float*   hE     = (float*)  alloc((size_t)2 * B * H * 4);       // zeroed with AfrEA
    ushortT* AfrEA  = (ushortT*)alloc((size_t)2 * B * H * 2 * 2);   // enc A planes ping
    ushortT* AfrEB  = (ushortT*)alloc((size_t)2 * B * H * 2 * 2);   // enc A planes pong
    float*   hh     = (float*)  alloc((size_t)B * H2 * 4);
    ushortT* AfrDA  = (ushortT*)alloc((size_t)B * H2 * 2 * 2);      // dec A planes ping
    ushortT* AfrDB  = (ushortT*)alloc((size_t)B * H2 * 2 * 2);      // dec A planes pong
    float*   giTabF = (float*)  alloc((size_t)VOUTD * H3 * 4);
    float*   giTabB = (float*)  alloc((size_t)VOUTD * H3 * 4);
    float*   giTabD = (float*)  alloc((size_t)VOUTD * H6 * 4);
    float*   giPart = (float*)  alloc((size_t)4 * VOUTD * H6 * 4);  // split-K partials
    ushortT* WfrF   = (ushortT*)alloc((size_t)H3 * H * 2 * 2);
    ushortT* WfrB   = (ushortT*)alloc((size_t)H3 * H * 2 * 2);
    ushortT* WfrD   = (ushortT*)alloc((size_t)H6 * H2 * 2 * 2);
    int*     tok    = (int*)    alloc((size_t)B * 4);
    size_t required = off;

    dim3 blk(256);

    if (ws_size >= required) {
        // =================== fragment-major fused path ===================
        {   // zero hE fp32 + AfrEA (contiguous)
            size_t zbytes = (size_t)2 * B * H * 4 + (size_t)2 * B * H * 4;
            int n16 = (int)(zbytes / 16);
            zero16<<<dim3((n16 + 255) / 256), blk, 0, stream>>>((uint4*)hE, n16);
        }
        // W -> fragment-major hi/lo (coalesced, wave per fragment)
        {
            int fe = (H / 16) * (H / 32) * 3;        // 6144
            int fd = (H2 / 16) * (H2 / 32) * 3;      // 24576
            swizzle_w<<<dim3((fe + 3) / 4), blk, 0, stream>>>(W_hh_f, WfrF, 10, 7);
            swizzle_w<<<dim3((fe + 3) / 4), blk, 0, stream>>>(W_hh_b, WfrB, 10, 7);
            swizzle_w<<<dim3((fd + 3) / 4), blk, 0, stream>>>(W_hh_d, WfrD, 11, 8);
        }

        // gi tables (exact fp32, split-K x4)
        gemm_sk<<<dim3(H3 / 64, VOUTD / 64, 4), blk, 0, stream>>>(
            enc_emb, E, W_ih_f, giPart, H3, E, 4);
        gi_combine<<<dim3(H3 / 256, VOUTD), blk, 0, stream>>>(giPart, b_ih_f, giTabF, H3, 4);
        gemm_sk<<<dim3(H3 / 64, VOUTD / 64, 4), blk, 0, stream>>>(
            enc_emb, E, W_ih_b, giPart, H3, E, 4);
        gi_combine<<<dim3(H3 / 256, VOUTD), blk, 0, stream>>>(giPart, b_ih_b, giTabB, H3, 4);
        gemm_sk<<<dim3(H6 / 64, VOUTD / 64, 4), blk, 0, stream>>>(
            dec_emb, E, W_ih_d, giPart, H6, E, 4);
        gi_combine<<<dim3(H6 / 256, VOUTD), blk, 0, stream>>>(giPart, b_ih_d, giTabD, H6, 4);

        // ---------------- Encoder: 64 fused steps ----------------
        for (int s = 0; s < S; ++s) {
            const ushortT* inA = (s & 1) ? AfrEB : AfrEA;
            ushortT* outA = (s & 1) ? AfrEA : AfrEB;
            fused_step_enc<<<dim3(512), blk, 0, stream>>>(
                inA, WfrF, WfrB, giTabF, giTabB, src, s, b_hh_f, b_hh_b, hE, outA);
        }

        init_hh_tok_split<<<dim3((B * H2) / 256), blk, 0, stream>>>(
            hE, hE + (size_t)B * H, tgt, hh, AfrDA, tok);

        // ---------------- Decoder: 31 fused steps ----------------
        for (int t = 0; t < T - 1; ++t) {
            const ushortT* inA = (t & 1) ? AfrDB : AfrDA;
            ushortT* outA = (t & 1) ? AfrDA : AfrDB;
            fused_step_dec<<<dim3(512), blk, 0, stream>>>(
                inA, WfrD, giTabD, tok, b_hh_d, hh, outA);
            logits_argmax2<<<dim3(B / 2), blk, 0, stream>>>(hh, W_fc, b_fc, out, tok, t);
        }
    } else {
        // =================== fp32 fallback (R1-proven path) ===================
        {
            size_t zbytes = (size_t)2 * B * H * 4;
            int n16 = (int)(zbytes / 16);
            zero16<<<dim3((n16 + 255) / 256), blk, 0, stream>>>((uint4*)hE, n16);
        }
        float* giE = (float*)WfrF;                       // scratch overlay
        float* ghF = giE + (size_t)2 * B * H3;
        dim3 grid_gi(H3 / 64, (2 * B) / 64);
        dim3 grid_gate((2 * B * H) / 256);
        for (int s = 0; s < S; ++s) {
            gemm_enc<<<grid_gi, blk, 0, stream>>>(enc_emb, E, E, src, s,
                                                  W_ih_f, b_ih_f, W_ih_b, b_ih_b, giE, H3);
            gemm_enc<<<grid_gi, blk, 0, stream>>>(hE, H, H, nullptr, 0,
                                                  W_hh_f, b_hh_f, W_hh_b, b_hh_b, ghF, H3);
            gru_gate<<<grid_gate, blk, 0, stream>>>(giE, ghF, hE, H);
        }
        init_hh_tok<<<dim3((B * H2) / 256), blk, 0, stream>>>(hE, hE + (size_t)B * H, tgt, hh, tok);
        dim3 grid_d(H6 / 64, B / 64);
        dim3 grid_dgate((B * H2) / 256);
        for (int t = 0; t < T - 1; ++t) {
            gemm_bias<<<grid_d, blk, 0, stream>>>(dec_emb, tok, 1, 0, E,
                                                  W_ih_d, b_ih_d, giE, H6, E);
            gemm_bias<<<grid_d, blk, 0, stream>>>(hh, nullptr, 0, 0, H2,
                                                  W_hh_d, b_hh_d, ghF, H6, H2);
            gru_gate<<<grid_dgate, blk, 0, stream>>>(giE, ghF, hh, H2);
            logits_argmax2<<<dim3(B / 2), blk, 0, stream>>>(hh, W_fc, b_fc, out, tok, t);
        }
    }
}